// Round 1
// baseline (6926.480 us; speedup 1.0000x reference)
//
#include <hip/hip_runtime.h>

#define NFEAT 512
#define NCLS  40

// ---------------------------------------------------------------------------
// Detect adj storage dtype. If adj is int64 (little-endian, values < 2^31),
// every odd 32-bit word is a zero high-half. If int32, odd words are random
// node indices (prob. all-zero over 32k samples ~ 0). flag!=0 => int32.
// ---------------------------------------------------------------------------
__global__ void detect_kernel(const unsigned int* __restrict__ w,
                              unsigned int* __restrict__ flag) {
    unsigned int v = 0;
    for (int i = 1 + 2 * (int)threadIdx.x; i < 65536; i += 2 * (int)blockDim.x)
        v |= w[i];
    if (v) atomicOr(flag, 1u);
}

// ---------------------------------------------------------------------------
// xw = x @ W^T   (N x 512) * (40 x 512)^T -> (N x 40)
// Thread-per-row; W accesses are wave-uniform -> scalar loads; x via float4.
// ---------------------------------------------------------------------------
__global__ void gemm_kernel(const float* __restrict__ x,
                            const float* __restrict__ W,
                            float* __restrict__ xw, int N) {
    int r = blockIdx.x * blockDim.x + threadIdx.x;
    if (r >= N) return;
    const float4* xr = reinterpret_cast<const float4*>(x) + (size_t)r * (NFEAT / 4);
    const float4* W4 = reinterpret_cast<const float4*>(W);
    float acc[NCLS];
#pragma unroll
    for (int c = 0; c < NCLS; ++c) acc[c] = 0.0f;
    for (int k4 = 0; k4 < NFEAT / 4; ++k4) {
        float4 xv = xr[k4];
#pragma unroll
        for (int c = 0; c < NCLS; ++c) {
            float4 wv = W4[c * (NFEAT / 4) + k4];   // uniform across wave
            acc[c] = fmaf(xv.x, wv.x, acc[c]);
            acc[c] = fmaf(xv.y, wv.y, acc[c]);
            acc[c] = fmaf(xv.z, wv.z, acc[c]);
            acc[c] = fmaf(xv.w, wv.w, acc[c]);
        }
    }
    float4* o4 = reinterpret_cast<float4*>(xw + (size_t)r * NCLS);
#pragma unroll
    for (int j = 0; j < NCLS / 4; ++j)
        o4[j] = make_float4(acc[4 * j + 0], acc[4 * j + 1],
                            acc[4 * j + 2], acc[4 * j + 3]);
}

// ---------------------------------------------------------------------------
// deg[c] = #{edges with col==c, row!=col}
// ---------------------------------------------------------------------------
__global__ void degree_kernel(const void* __restrict__ adj,
                              const unsigned int* __restrict__ flag,
                              int* __restrict__ deg, int E) {
    int e = blockIdx.x * blockDim.x + threadIdx.x;
    if (e >= E) return;
    int r, c;
    if (*flag) {
        const int* a = (const int*)adj;
        r = a[e]; c = a[(size_t)E + e];
    } else {
        const long long* a = (const long long*)adj;
        r = (int)a[e]; c = (int)a[(size_t)E + e];
    }
    if (r != c) atomicAdd(&deg[c], 1);
}

// dinv[i] = 1 / (deg[i] + 1)   (+1 = appended self-loop; always > 0)
__global__ void dinv_kernel(const int* __restrict__ deg,
                            float* __restrict__ dinv, int N) {
    int i = blockIdx.x * blockDim.x + threadIdx.x;
    if (i < N) dinv[i] = 1.0f / (float)(deg[i] + 1);
}

// ---------------------------------------------------------------------------
// out[i][:] = dinv[i] * xw[i][:] + b[:]     (self-loop term + bias, non-atomic)
// One thread per float4 (N * 10 threads).
// ---------------------------------------------------------------------------
__global__ void init_kernel(const float* __restrict__ xw,
                            const float* __restrict__ dinv,
                            const float* __restrict__ b,
                            float* __restrict__ out, int N) {
    int idx = blockIdx.x * blockDim.x + threadIdx.x;
    int total = N * (NCLS / 4);
    if (idx >= total) return;
    int i = idx / (NCLS / 4);
    int j = idx % (NCLS / 4);
    float s = dinv[i];
    float4 v = reinterpret_cast<const float4*>(xw)[idx];
    float4 bb = reinterpret_cast<const float4*>(b)[j];
    float4 o;
    o.x = fmaf(s, v.x, bb.x);
    o.y = fmaf(s, v.y, bb.y);
    o.z = fmaf(s, v.z, bb.z);
    o.w = fmaf(s, v.w, bb.w);
    reinterpret_cast<float4*>(out)[idx] = o;
}

// ---------------------------------------------------------------------------
// For each non-self-loop edge (r, c): out[c][:] += dinv[c] * xw[r][:]
// ---------------------------------------------------------------------------
__global__ void scatter_kernel(const void* __restrict__ adj,
                               const unsigned int* __restrict__ flag,
                               const float* __restrict__ xw,
                               const float* __restrict__ dinv,
                               float* __restrict__ out, int E) {
    int e = blockIdx.x * blockDim.x + threadIdx.x;
    if (e >= E) return;
    int r, c;
    if (*flag) {
        const int* a = (const int*)adj;
        r = a[e]; c = a[(size_t)E + e];
    } else {
        const long long* a = (const long long*)adj;
        r = (int)a[e]; c = (int)a[(size_t)E + e];
    }
    if (r == c) return;
    float s = dinv[c];
    const float4* xr = reinterpret_cast<const float4*>(xw + (size_t)r * NCLS);
    float* o = out + (size_t)c * NCLS;
#pragma unroll
    for (int j = 0; j < NCLS / 4; ++j) {
        float4 v = xr[j];
        atomicAdd(o + 4 * j + 0, s * v.x);
        atomicAdd(o + 4 * j + 1, s * v.y);
        atomicAdd(o + 4 * j + 2, s * v.z);
        atomicAdd(o + 4 * j + 3, s * v.w);
    }
}

extern "C" void kernel_launch(void* const* d_in, const int* in_sizes, int n_in,
                              void* d_out, int out_size, void* d_ws, size_t ws_size,
                              hipStream_t stream) {
    const float* x   = (const float*)d_in[0];
    const void*  adj = d_in[1];
    const float* W   = (const float*)d_in[2];
    const float* b   = (const float*)d_in[3];
    float* out = (float*)d_out;

    const int N = in_sizes[0] / NFEAT;   // 100000
    const int E = in_sizes[1] / 2;       // 3200000

    // workspace layout (16B-aligned):
    //   [0, N*40*4)                    xw
    //   [XW, XW + N*4)                 deg (int)
    //   [XW + N*4, +16)                flag
    //   [XW + N*4 + 16, +N*4)          dinv
    char* ws = (char*)d_ws;
    const size_t XW_BYTES = (size_t)N * NCLS * sizeof(float);
    float* xw  = (float*)ws;
    int*   deg = (int*)(ws + XW_BYTES);
    unsigned int* flag = (unsigned int*)(ws + XW_BYTES + (size_t)N * 4);
    float* dinv = (float*)(ws + XW_BYTES + (size_t)N * 4 + 16);

    // zero deg + flag each call (harness does not re-poison between replays)
    hipMemsetAsync(deg, 0, (size_t)N * 4 + 16, stream);

    detect_kernel<<<1, 512, 0, stream>>>((const unsigned int*)adj, flag);
    gemm_kernel<<<(N + 255) / 256, 256, 0, stream>>>(x, W, xw, N);
    degree_kernel<<<(E + 255) / 256, 256, 0, stream>>>(adj, flag, deg, E);
    dinv_kernel<<<(N + 255) / 256, 256, 0, stream>>>(deg, dinv, N);
    init_kernel<<<(N * (NCLS / 4) + 255) / 256, 256, 0, stream>>>(xw, dinv, b, out, N);
    scatter_kernel<<<(E + 255) / 256, 256, 0, stream>>>(adj, flag, xw, dinv, out, E);
}

// Round 2
// 913.767 us; speedup vs baseline: 7.5801x; 7.5801x over previous
//
#include <hip/hip_runtime.h>

#define NFEAT 512
#define NCLS  40
#define SCAN_CHUNK 1024   // elements per scan block (256 threads x 4)

// ---------------------------------------------------------------------------
// Detect adj storage dtype. int64 (values < 2^31, LE) => odd 32-bit words all
// zero. int32 => odd words are random node ids. flag!=0 => int32.
// ---------------------------------------------------------------------------
__global__ void detect_kernel(const unsigned int* __restrict__ w,
                              unsigned int* __restrict__ flag) {
    unsigned int v = 0;
    for (int i = 1 + 2 * (int)threadIdx.x; i < 65536; i += 2 * (int)blockDim.x)
        v |= w[i];
    if (v) atomicOr(flag, 1u);
}

__device__ __forceinline__ void load_edge(const void* adj, int int32_mode,
                                          int e, int E, int& r, int& c) {
    if (int32_mode) {
        const int* a = (const int*)adj;
        r = a[e]; c = a[(size_t)E + e];
    } else {
        const long long* a = (const long long*)adj;
        r = (int)a[e]; c = (int)a[(size_t)E + e];
    }
}

// ---------------------------------------------------------------------------
// xw = x @ W^T   (N x 512) * (40 x 512)^T -> (N x 40)
// ---------------------------------------------------------------------------
__global__ void gemm_kernel(const float* __restrict__ x,
                            const float* __restrict__ W,
                            float* __restrict__ xw, int N) {
    int r = blockIdx.x * blockDim.x + threadIdx.x;
    if (r >= N) return;
    const float4* xr = reinterpret_cast<const float4*>(x) + (size_t)r * (NFEAT / 4);
    const float4* W4 = reinterpret_cast<const float4*>(W);
    float acc[NCLS];
#pragma unroll
    for (int c = 0; c < NCLS; ++c) acc[c] = 0.0f;
    for (int k4 = 0; k4 < NFEAT / 4; ++k4) {
        float4 xv = xr[k4];
#pragma unroll
        for (int c = 0; c < NCLS; ++c) {
            float4 wv = W4[c * (NFEAT / 4) + k4];   // uniform across wave
            acc[c] = fmaf(xv.x, wv.x, acc[c]);
            acc[c] = fmaf(xv.y, wv.y, acc[c]);
            acc[c] = fmaf(xv.z, wv.z, acc[c]);
            acc[c] = fmaf(xv.w, wv.w, acc[c]);
        }
    }
    float4* o4 = reinterpret_cast<float4*>(xw + (size_t)r * NCLS);
#pragma unroll
    for (int j = 0; j < NCLS / 4; ++j)
        o4[j] = make_float4(acc[4 * j + 0], acc[4 * j + 1],
                            acc[4 * j + 2], acc[4 * j + 3]);
}

// ---------------------------------------------------------------------------
// deg[c] = #{edges with col==c, row!=col}   (int atomics, 3.2M)
// ---------------------------------------------------------------------------
__global__ void degree_kernel(const void* __restrict__ adj,
                              const unsigned int* __restrict__ flag,
                              int* __restrict__ deg, int E) {
    int e = blockIdx.x * blockDim.x + threadIdx.x;
    if (e >= E) return;
    int r, c;
    load_edge(adj, *flag, e, E, r, c);
    if (r != c) atomicAdd(&deg[c], 1);
}

// ---------------------------------------------------------------------------
// 3-kernel exclusive scan of deg[0..N) -> starts (and a cursor copy)
// ---------------------------------------------------------------------------
__global__ void scan_partial_kernel(const int* __restrict__ deg,
                                    int* __restrict__ bsum, int N) {
    __shared__ int sdata[256];
    int base = blockIdx.x * SCAN_CHUNK + threadIdx.x * 4;
    int s = 0;
#pragma unroll
    for (int k = 0; k < 4; ++k) {
        int i = base + k;
        s += (i < N) ? deg[i] : 0;
    }
    sdata[threadIdx.x] = s;
    __syncthreads();
    for (int o = 128; o > 0; o >>= 1) {
        if (threadIdx.x < o) sdata[threadIdx.x] += sdata[threadIdx.x + o];
        __syncthreads();
    }
    if (threadIdx.x == 0) bsum[blockIdx.x] = sdata[0];
}

__global__ void scan_bsum_kernel(int* __restrict__ bsum, int nblk) {
    if (threadIdx.x == 0) {
        int acc = 0;
        for (int i = 0; i < nblk; ++i) {
            int v = bsum[i];
            bsum[i] = acc;      // in-place exclusive scan (serial; nblk ~ 98)
            acc += v;
        }
    }
}

__global__ void scan_final_kernel(const int* __restrict__ deg,
                                  const int* __restrict__ bsum,
                                  int* __restrict__ starts,
                                  int* __restrict__ cursor, int N) {
    __shared__ int sdata[256];
    int t = threadIdx.x;
    int base = blockIdx.x * SCAN_CHUNK + t * 4;
    int d[4];
#pragma unroll
    for (int k = 0; k < 4; ++k) {
        int i = base + k;
        d[k] = (i < N) ? deg[i] : 0;
    }
    int s = d[0] + d[1] + d[2] + d[3];
    sdata[t] = s;
    __syncthreads();
    // Hillis-Steele inclusive scan over 256 thread-sums
    for (int o = 1; o < 256; o <<= 1) {
        int v = (t >= o) ? sdata[t - o] : 0;
        __syncthreads();
        sdata[t] += v;
        __syncthreads();
    }
    int off = bsum[blockIdx.x] + sdata[t] - s;   // exclusive prefix for thread
    int run = 0;
#pragma unroll
    for (int k = 0; k < 4; ++k) {
        int i = base + k;
        if (i < N) {
            starts[i] = off + run;
            cursor[i] = off + run;
        }
        run += d[k];
    }
}

// ---------------------------------------------------------------------------
// Bucket fill: src[pos] = row for each non-self-loop edge, grouped by col.
// ---------------------------------------------------------------------------
__global__ void bucket_kernel(const void* __restrict__ adj,
                              const unsigned int* __restrict__ flag,
                              int* __restrict__ cursor,
                              int* __restrict__ src, int E) {
    int e = blockIdx.x * blockDim.x + threadIdx.x;
    if (e >= E) return;
    int r, c;
    load_edge(adj, *flag, e, E, r, c);
    if (r == c) return;
    int pos = atomicAdd(&cursor[c], 1);
    src[pos] = r;
}

// ---------------------------------------------------------------------------
// Gather: one wave per node. lanes 0..39 each own one class.
// out[c][j] = (xw[c][j] + sum_e xw[src_e][j]) / (deg[c]+1) + b[j]
// ---------------------------------------------------------------------------
__global__ void gather_kernel(const float* __restrict__ xw,
                              const int* __restrict__ starts,
                              const int* __restrict__ deg,
                              const int* __restrict__ src,
                              const float* __restrict__ b,
                              float* __restrict__ out, int N) {
    int wid = (blockIdx.x * blockDim.x + threadIdx.x) >> 6;
    int lane = threadIdx.x & 63;
    if (wid >= N) return;
    int start = starts[wid];
    int d = deg[wid];
    float scale = 1.0f / (float)(d + 1);
    float acc = 0.0f;
    if (lane < NCLS) acc = xw[(size_t)wid * NCLS + lane];
    for (int e = 0; e < d; ++e) {
        int r = src[start + e];                    // wave-uniform broadcast
        if (lane < NCLS) acc += xw[(size_t)r * NCLS + lane];
    }
    if (lane < NCLS)
        out[(size_t)wid * NCLS + lane] = fmaf(scale, acc, b[lane]);
}

extern "C" void kernel_launch(void* const* d_in, const int* in_sizes, int n_in,
                              void* d_out, int out_size, void* d_ws, size_t ws_size,
                              hipStream_t stream) {
    const float* x   = (const float*)d_in[0];
    const void*  adj = d_in[1];
    const float* W   = (const float*)d_in[2];
    const float* b   = (const float*)d_in[3];
    float* out = (float*)d_out;

    const int N = in_sizes[0] / NFEAT;   // 100000
    const int E = in_sizes[1] / 2;       // 3200000
    const int NBLK = (N + SCAN_CHUNK - 1) / SCAN_CHUNK;

    // workspace layout (16B-aligned pieces)
    char* ws = (char*)d_ws;
    size_t off = 0;
    auto alloc = [&](size_t bytes) { char* p = ws + off; off += (bytes + 15) & ~size_t(15); return p; };
    float* xw          = (float*)alloc((size_t)N * NCLS * sizeof(float)); // 16 MB
    int*   deg         = (int*)  alloc((size_t)N * sizeof(int));
    int*   starts      = (int*)  alloc((size_t)N * sizeof(int));
    int*   cursor      = (int*)  alloc((size_t)N * sizeof(int));
    int*   bsum        = (int*)  alloc((size_t)NBLK * sizeof(int));
    unsigned int* flag = (unsigned int*)alloc(16);
    int*   src         = (int*)  alloc((size_t)E * sizeof(int));          // 12.8 MB

    // zero deg + flag each call (cursor/starts/bsum are fully overwritten)
    hipMemsetAsync(deg, 0, (size_t)N * sizeof(int), stream);
    hipMemsetAsync(flag, 0, 16, stream);

    detect_kernel<<<1, 512, 0, stream>>>((const unsigned int*)adj, flag);
    gemm_kernel<<<(N + 255) / 256, 256, 0, stream>>>(x, W, xw, N);
    degree_kernel<<<(E + 255) / 256, 256, 0, stream>>>(adj, flag, deg, E);
    scan_partial_kernel<<<NBLK, 256, 0, stream>>>(deg, bsum, N);
    scan_bsum_kernel<<<1, 64, 0, stream>>>(bsum, NBLK);
    scan_final_kernel<<<NBLK, 256, 0, stream>>>(deg, bsum, starts, cursor, N);
    bucket_kernel<<<(E + 255) / 256, 256, 0, stream>>>(adj, flag, cursor, src, E);
    gather_kernel<<<(N * 64 + 255) / 256, 256, 0, stream>>>(xw, starts, deg, src, b, out, N);
}

// Round 3
// 752.526 us; speedup vs baseline: 9.2043x; 1.2143x over previous
//
#include <hip/hip_runtime.h>

#define NFEAT 512
#define NCLS  40
#define SCAN_CHUNK 1024   // elements per scan block (256 threads x 4)

// ---------------------------------------------------------------------------
// Detect adj storage dtype. int64 (values < 2^31, LE) => odd 32-bit words all
// zero. int32 => odd words are random node ids. flag!=0 => int32.
// ---------------------------------------------------------------------------
__global__ void detect_kernel(const unsigned int* __restrict__ w,
                              unsigned int* __restrict__ flag) {
    unsigned int v = 0;
    for (int i = 1 + 2 * (int)threadIdx.x; i < 65536; i += 2 * (int)blockDim.x)
        v |= w[i];
    if (v) atomicOr(flag, 1u);
}

__device__ __forceinline__ void load_edge(const void* adj, int int32_mode,
                                          int e, int E, int& r, int& c) {
    if (int32_mode) {
        const int* a = (const int*)adj;
        r = a[e]; c = a[(size_t)E + e];
    } else {
        const long long* a = (const long long*)adj;
        r = (int)a[e]; c = (int)a[(size_t)E + e];
    }
}

// ---------------------------------------------------------------------------
// xw = x @ W^T   (N x 512) * (40 x 512)^T -> (N x 40)
// ---------------------------------------------------------------------------
__global__ void gemm_kernel(const float* __restrict__ x,
                            const float* __restrict__ W,
                            float* __restrict__ xw, int N) {
    int r = blockIdx.x * blockDim.x + threadIdx.x;
    if (r >= N) return;
    const float4* xr = reinterpret_cast<const float4*>(x) + (size_t)r * (NFEAT / 4);
    const float4* W4 = reinterpret_cast<const float4*>(W);
    float acc[NCLS];
#pragma unroll
    for (int c = 0; c < NCLS; ++c) acc[c] = 0.0f;
    for (int k4 = 0; k4 < NFEAT / 4; ++k4) {
        float4 xv = xr[k4];
#pragma unroll
        for (int c = 0; c < NCLS; ++c) {
            float4 wv = W4[c * (NFEAT / 4) + k4];   // thread-invariant -> scalarizable
            acc[c] = fmaf(xv.x, wv.x, acc[c]);
            acc[c] = fmaf(xv.y, wv.y, acc[c]);
            acc[c] = fmaf(xv.z, wv.z, acc[c]);
            acc[c] = fmaf(xv.w, wv.w, acc[c]);
        }
    }
    float4* o4 = reinterpret_cast<float4*>(xw + (size_t)r * NCLS);
#pragma unroll
    for (int j = 0; j < NCLS / 4; ++j)
        o4[j] = make_float4(acc[4 * j + 0], acc[4 * j + 1],
                            acc[4 * j + 2], acc[4 * j + 3]);
}

// ---------------------------------------------------------------------------
// deg[c] = #{edges with col==c, row!=col}   (int atomics, 3.2M)
// ---------------------------------------------------------------------------
__global__ void degree_kernel(const void* __restrict__ adj,
                              const unsigned int* __restrict__ flag,
                              int* __restrict__ deg, int E) {
    int e = blockIdx.x * blockDim.x + threadIdx.x;
    if (e >= E) return;
    int r, c;
    load_edge(adj, *flag, e, E, r, c);
    if (r != c) atomicAdd(&deg[c], 1);
}

// ---------------------------------------------------------------------------
// 3-kernel exclusive scan of deg[0..N) -> starts (and a cursor copy)
// ---------------------------------------------------------------------------
__global__ void scan_partial_kernel(const int* __restrict__ deg,
                                    int* __restrict__ bsum, int N) {
    __shared__ int sdata[256];
    int base = blockIdx.x * SCAN_CHUNK + threadIdx.x * 4;
    int s = 0;
#pragma unroll
    for (int k = 0; k < 4; ++k) {
        int i = base + k;
        s += (i < N) ? deg[i] : 0;
    }
    sdata[threadIdx.x] = s;
    __syncthreads();
    for (int o = 128; o > 0; o >>= 1) {
        if (threadIdx.x < o) sdata[threadIdx.x] += sdata[threadIdx.x + o];
        __syncthreads();
    }
    if (threadIdx.x == 0) bsum[blockIdx.x] = sdata[0];
}

__global__ void scan_bsum_kernel(int* __restrict__ bsum, int nblk) {
    if (threadIdx.x == 0) {
        int acc = 0;
        for (int i = 0; i < nblk; ++i) {
            int v = bsum[i];
            bsum[i] = acc;      // in-place exclusive scan (serial; nblk ~ 98)
            acc += v;
        }
    }
}

__global__ void scan_final_kernel(const int* __restrict__ deg,
                                  const int* __restrict__ bsum,
                                  int* __restrict__ starts,
                                  int* __restrict__ cursor, int N) {
    __shared__ int sdata[256];
    int t = threadIdx.x;
    int base = blockIdx.x * SCAN_CHUNK + t * 4;
    int d[4];
#pragma unroll
    for (int k = 0; k < 4; ++k) {
        int i = base + k;
        d[k] = (i < N) ? deg[i] : 0;
    }
    int s = d[0] + d[1] + d[2] + d[3];
    sdata[t] = s;
    __syncthreads();
    // Hillis-Steele inclusive scan over 256 thread-sums
    for (int o = 1; o < 256; o <<= 1) {
        int v = (t >= o) ? sdata[t - o] : 0;
        __syncthreads();
        sdata[t] += v;
        __syncthreads();
    }
    int off = bsum[blockIdx.x] + sdata[t] - s;   // exclusive prefix for thread
    int run = 0;
#pragma unroll
    for (int k = 0; k < 4; ++k) {
        int i = base + k;
        if (i < N) {
            starts[i] = off + run;
            cursor[i] = off + run;
        }
        run += d[k];
    }
}

// ---------------------------------------------------------------------------
// Bucket fill: src[pos] = row for each non-self-loop edge, grouped by col.
// ---------------------------------------------------------------------------
__global__ void bucket_kernel(const void* __restrict__ adj,
                              const unsigned int* __restrict__ flag,
                              int* __restrict__ cursor,
                              int* __restrict__ src, int E) {
    int e = blockIdx.x * blockDim.x + threadIdx.x;
    if (e >= E) return;
    int r, c;
    load_edge(adj, *flag, e, E, r, c);
    if (r == c) return;
    int pos = atomicAdd(&cursor[c], 1);
    src[pos] = r;
}

// ---------------------------------------------------------------------------
// Gather: one wave per node. lanes 0..39 each own one class.
// out[c][j] = (xw[c][j] + sum_e xw[src_e][j]) / (deg[c]+1) + b[j]
// Edge loop unrolled x8: 8 independent src loads then 8 independent row
// loads in flight per wave (MLP ~8x vs serial loop).
// ---------------------------------------------------------------------------
__global__ void gather_kernel(const float* __restrict__ xw,
                              const int* __restrict__ starts,
                              const int* __restrict__ deg,
                              const int* __restrict__ src,
                              const float* __restrict__ b,
                              float* __restrict__ out, int N) {
    int wid = (blockIdx.x * blockDim.x + threadIdx.x) >> 6;
    int lane = threadIdx.x & 63;
    if (wid >= N) return;
    int start = __builtin_amdgcn_readfirstlane(starts[wid]);
    int d     = __builtin_amdgcn_readfirstlane(deg[wid]);
    float scale = 1.0f / (float)(d + 1);
    bool act = lane < NCLS;
    const float* xwl = xw + lane;
    float acc = act ? xw[(size_t)wid * NCLS + lane] : 0.0f;
    const int* sp = src + start;
    int e = 0;
    for (; e + 8 <= d; e += 8) {
        int r0 = sp[e + 0], r1 = sp[e + 1], r2 = sp[e + 2], r3 = sp[e + 3];
        int r4 = sp[e + 4], r5 = sp[e + 5], r6 = sp[e + 6], r7 = sp[e + 7];
        float v0 = 0, v1 = 0, v2 = 0, v3 = 0, v4 = 0, v5 = 0, v6 = 0, v7 = 0;
        if (act) {
            v0 = xwl[(size_t)r0 * NCLS];
            v1 = xwl[(size_t)r1 * NCLS];
            v2 = xwl[(size_t)r2 * NCLS];
            v3 = xwl[(size_t)r3 * NCLS];
            v4 = xwl[(size_t)r4 * NCLS];
            v5 = xwl[(size_t)r5 * NCLS];
            v6 = xwl[(size_t)r6 * NCLS];
            v7 = xwl[(size_t)r7 * NCLS];
        }
        acc += ((v0 + v1) + (v2 + v3)) + ((v4 + v5) + (v6 + v7));
    }
    for (; e < d; ++e) {
        int r = sp[e];
        if (act) acc += xwl[(size_t)r * NCLS];
    }
    if (act) out[(size_t)wid * NCLS + lane] = fmaf(scale, acc, b[lane]);
}

extern "C" void kernel_launch(void* const* d_in, const int* in_sizes, int n_in,
                              void* d_out, int out_size, void* d_ws, size_t ws_size,
                              hipStream_t stream) {
    const float* x   = (const float*)d_in[0];
    const void*  adj = d_in[1];
    const float* W   = (const float*)d_in[2];
    const float* b   = (const float*)d_in[3];
    float* out = (float*)d_out;

    const int N = in_sizes[0] / NFEAT;   // 100000
    const int E = in_sizes[1] / 2;       // 3200000
    const int NBLK = (N + SCAN_CHUNK - 1) / SCAN_CHUNK;

    // workspace layout (16B-aligned pieces)
    char* ws = (char*)d_ws;
    size_t off = 0;
    auto alloc = [&](size_t bytes) { char* p = ws + off; off += (bytes + 15) & ~size_t(15); return p; };
    float* xw          = (float*)alloc((size_t)N * NCLS * sizeof(float)); // 16 MB
    int*   deg         = (int*)  alloc((size_t)N * sizeof(int));
    int*   starts      = (int*)  alloc((size_t)N * sizeof(int));
    int*   cursor      = (int*)  alloc((size_t)N * sizeof(int));
    int*   bsum        = (int*)  alloc((size_t)NBLK * sizeof(int));
    unsigned int* flag = (unsigned int*)alloc(16);
    int*   src         = (int*)  alloc((size_t)E * sizeof(int));          // 12.8 MB

    // zero deg + flag each call (cursor/starts/bsum are fully overwritten)
    hipMemsetAsync(deg, 0, (size_t)N * sizeof(int), stream);
    hipMemsetAsync(flag, 0, 16, stream);

    detect_kernel<<<1, 512, 0, stream>>>((const unsigned int*)adj, flag);
    gemm_kernel<<<(N + 255) / 256, 256, 0, stream>>>(x, W, xw, N);
    degree_kernel<<<(E + 255) / 256, 256, 0, stream>>>(adj, flag, deg, E);
    scan_partial_kernel<<<NBLK, 256, 0, stream>>>(deg, bsum, N);
    scan_bsum_kernel<<<1, 64, 0, stream>>>(bsum, NBLK);
    scan_final_kernel<<<NBLK, 256, 0, stream>>>(deg, bsum, starts, cursor, N);
    bucket_kernel<<<(E + 255) / 256, 256, 0, stream>>>(adj, flag, cursor, src, E);
    gather_kernel<<<(N * 64 + 255) / 256, 256, 0, stream>>>(xw, starts, deg, src, b, out, N);
}

// Round 5
// 600.989 us; speedup vs baseline: 11.5251x; 1.2521x over previous
//
#include <hip/hip_runtime.h>

#define NFEAT 512
#define NCLS  40
#define SCAN_CHUNK 1024   // elements per scan block (256 threads x 4)
#define DM 128            // padded bucket width (max in-degree ~65 for this graph)

// ---------------------------------------------------------------------------
// Detect adj storage dtype. int64 (values < 2^31, LE) => odd 32-bit words all
// zero. int32 => odd words are random node ids. flag!=0 => int32.
// ---------------------------------------------------------------------------
__global__ void detect_kernel(const unsigned int* __restrict__ w,
                              unsigned int* __restrict__ flag) {
    unsigned int v = 0;
    for (int i = 1 + 2 * (int)threadIdx.x; i < 65536; i += 2 * (int)blockDim.x)
        v |= w[i];
    if (v) atomicOr(flag, 1u);
}

__device__ __forceinline__ void load_edge(const void* adj, int int32_mode,
                                          int e, int E, int& r, int& c) {
    if (int32_mode) {
        const int* a = (const int*)adj;
        r = a[e]; c = a[(size_t)E + e];
    } else {
        const long long* a = (const long long*)adj;
        r = (int)a[e]; c = (int)a[(size_t)E + e];
    }
}

// ---------------------------------------------------------------------------
// xw = x @ W^T   (N x 512) * (40 x 512)^T -> (N x 40)
// ---------------------------------------------------------------------------
__global__ void gemm_kernel(const float* __restrict__ x,
                            const float* __restrict__ W,
                            float* __restrict__ xw, int N) {
    int r = blockIdx.x * blockDim.x + threadIdx.x;
    if (r >= N) return;
    const float4* xr = reinterpret_cast<const float4*>(x) + (size_t)r * (NFEAT / 4);
    const float4* W4 = reinterpret_cast<const float4*>(W);
    float acc[NCLS];
#pragma unroll
    for (int c = 0; c < NCLS; ++c) acc[c] = 0.0f;
    for (int k4 = 0; k4 < NFEAT / 4; ++k4) {
        float4 xv = xr[k4];
#pragma unroll
        for (int c = 0; c < NCLS; ++c) {
            float4 wv = W4[c * (NFEAT / 4) + k4];   // thread-invariant -> scalarizable
            acc[c] = fmaf(xv.x, wv.x, acc[c]);
            acc[c] = fmaf(xv.y, wv.y, acc[c]);
            acc[c] = fmaf(xv.z, wv.z, acc[c]);
            acc[c] = fmaf(xv.w, wv.w, acc[c]);
        }
    }
    float4* o4 = reinterpret_cast<float4*>(xw + (size_t)r * NCLS);
#pragma unroll
    for (int j = 0; j < NCLS / 4; ++j)
        o4[j] = make_float4(acc[4 * j + 0], acc[4 * j + 1],
                            acc[4 * j + 2], acc[4 * j + 3]);
}

// ---------------------------------------------------------------------------
// DIRECT PATH: single-pass rank placement.
// For each non-self-loop edge (r,c): rank = cnt[c]++; src2[c*DM+rank] = r.
// cnt[] ends up = in-degree. One 3.2M-atomic pass instead of two + scans.
// Index guards: an OOB write here is a process-killing fault; never trust
// indices derived from a runtime dtype detection.
// ---------------------------------------------------------------------------
__global__ void fused_bucket_kernel(const void* __restrict__ adj,
                                    const unsigned int* __restrict__ flag,
                                    int* __restrict__ cnt,
                                    int* __restrict__ src2, int E, int N) {
    int e = blockIdx.x * blockDim.x + threadIdx.x;
    if (e >= E) return;
    int r, c;
    load_edge(adj, *flag, e, E, r, c);
    if (r == c) return;
    if ((unsigned)r >= (unsigned)N || (unsigned)c >= (unsigned)N) return;
    int pos = atomicAdd(&cnt[c], 1);
    if (pos < DM) src2[(size_t)c * DM + pos] = r;   // clamp guard (never hit here)
}

// ---------------------------------------------------------------------------
// FALLBACK PATH (ws too small): two-pass CSR via degree + scan + bucket.
// ---------------------------------------------------------------------------
__global__ void degree_kernel(const void* __restrict__ adj,
                              const unsigned int* __restrict__ flag,
                              int* __restrict__ deg, int E, int N) {
    int e = blockIdx.x * blockDim.x + threadIdx.x;
    if (e >= E) return;
    int r, c;
    load_edge(adj, *flag, e, E, r, c);
    if (r == c) return;
    if ((unsigned)r >= (unsigned)N || (unsigned)c >= (unsigned)N) return;
    atomicAdd(&deg[c], 1);
}

__global__ void scan_partial_kernel(const int* __restrict__ deg,
                                    int* __restrict__ bsum, int N) {
    __shared__ int sdata[256];
    int base = blockIdx.x * SCAN_CHUNK + threadIdx.x * 4;
    int s = 0;
#pragma unroll
    for (int k = 0; k < 4; ++k) {
        int i = base + k;
        s += (i < N) ? deg[i] : 0;
    }
    sdata[threadIdx.x] = s;
    __syncthreads();
    for (int o = 128; o > 0; o >>= 1) {
        if (threadIdx.x < o) sdata[threadIdx.x] += sdata[threadIdx.x + o];
        __syncthreads();
    }
    if (threadIdx.x == 0) bsum[blockIdx.x] = sdata[0];
}

__global__ void scan_bsum_kernel(int* __restrict__ bsum, int nblk) {
    if (threadIdx.x == 0) {
        int acc = 0;
        for (int i = 0; i < nblk; ++i) {
            int v = bsum[i];
            bsum[i] = acc;
            acc += v;
        }
    }
}

__global__ void scan_final_kernel(const int* __restrict__ deg,
                                  const int* __restrict__ bsum,
                                  int* __restrict__ starts,
                                  int* __restrict__ cursor, int N) {
    __shared__ int sdata[256];
    int t = threadIdx.x;
    int base = blockIdx.x * SCAN_CHUNK + t * 4;
    int d[4];
#pragma unroll
    for (int k = 0; k < 4; ++k) {
        int i = base + k;
        d[k] = (i < N) ? deg[i] : 0;
    }
    int s = d[0] + d[1] + d[2] + d[3];
    sdata[t] = s;
    __syncthreads();
    for (int o = 1; o < 256; o <<= 1) {
        int v = (t >= o) ? sdata[t - o] : 0;
        __syncthreads();
        sdata[t] += v;
        __syncthreads();
    }
    int off = bsum[blockIdx.x] + sdata[t] - s;
    int run = 0;
#pragma unroll
    for (int k = 0; k < 4; ++k) {
        int i = base + k;
        if (i < N) {
            starts[i] = off + run;
            cursor[i] = off + run;
        }
        run += d[k];
    }
}

__global__ void bucket_kernel(const void* __restrict__ adj,
                              const unsigned int* __restrict__ flag,
                              int* __restrict__ cursor,
                              int* __restrict__ src, int E, int N) {
    int e = blockIdx.x * blockDim.x + threadIdx.x;
    if (e >= E) return;
    int r, c;
    load_edge(adj, *flag, e, E, r, c);
    if (r == c) return;
    if ((unsigned)r >= (unsigned)N || (unsigned)c >= (unsigned)N) return;
    int pos = atomicAdd(&cursor[c], 1);
    src[pos] = r;
}

// ---------------------------------------------------------------------------
// Gather: one wave per node, lanes 0..39 own one class each.
// dm > 0: direct mode (start = wid*dm, d = min(cnt,dm)); dm == 0: CSR mode.
// ---------------------------------------------------------------------------
__global__ void gather_kernel(const float* __restrict__ xw,
                              const int* __restrict__ starts,
                              const int* __restrict__ deg,
                              const int* __restrict__ src,
                              const float* __restrict__ b,
                              float* __restrict__ out, int N, int dm) {
    int wid = (blockIdx.x * blockDim.x + threadIdx.x) >> 6;
    int lane = threadIdx.x & 63;
    if (wid >= N) return;
    int start, d;
    if (dm > 0) {
        start = wid * dm;
        d = __builtin_amdgcn_readfirstlane(min(deg[wid], dm));
    } else {
        start = __builtin_amdgcn_readfirstlane(starts[wid]);
        d = __builtin_amdgcn_readfirstlane(deg[wid]);
    }
    float scale = 1.0f / (float)(d + 1);
    bool act = lane < NCLS;
    const float* xwl = xw + lane;
    float acc = act ? xw[(size_t)wid * NCLS + lane] : 0.0f;
    const int* sp = src + start;
    int e = 0;
    for (; e + 8 <= d; e += 8) {
        int r0 = sp[e + 0], r1 = sp[e + 1], r2 = sp[e + 2], r3 = sp[e + 3];
        int r4 = sp[e + 4], r5 = sp[e + 5], r6 = sp[e + 6], r7 = sp[e + 7];
        float v0 = 0, v1 = 0, v2 = 0, v3 = 0, v4 = 0, v5 = 0, v6 = 0, v7 = 0;
        if (act) {
            v0 = xwl[(size_t)r0 * NCLS];
            v1 = xwl[(size_t)r1 * NCLS];
            v2 = xwl[(size_t)r2 * NCLS];
            v3 = xwl[(size_t)r3 * NCLS];
            v4 = xwl[(size_t)r4 * NCLS];
            v5 = xwl[(size_t)r5 * NCLS];
            v6 = xwl[(size_t)r6 * NCLS];
            v7 = xwl[(size_t)r7 * NCLS];
        }
        acc += ((v0 + v1) + (v2 + v3)) + ((v4 + v5) + (v6 + v7));
    }
    for (; e < d; ++e) {
        int r = sp[e];
        if (act) acc += xwl[(size_t)r * NCLS];
    }
    if (act) out[(size_t)wid * NCLS + lane] = fmaf(scale, acc, b[lane]);
}

extern "C" void kernel_launch(void* const* d_in, const int* in_sizes, int n_in,
                              void* d_out, int out_size, void* d_ws, size_t ws_size,
                              hipStream_t stream) {
    const float* x   = (const float*)d_in[0];
    const void*  adj = d_in[1];
    const float* W   = (const float*)d_in[2];
    const float* b   = (const float*)d_in[3];
    float* out = (float*)d_out;

    const int N = in_sizes[0] / NFEAT;   // 100000
    const int E = in_sizes[1] / 2;       // 3200000

    char* ws = (char*)d_ws;
    size_t off = 0;
    auto alloc = [&](size_t bytes) { char* p = ws + off; off += (bytes + 15) & ~size_t(15); return p; };

    float* xw          = (float*)alloc((size_t)N * NCLS * sizeof(float)); // 16 MB
    int*   cnt         = (int*)  alloc((size_t)N * sizeof(int));          // deg/cursor
    unsigned int* flag = (unsigned int*)alloc(16);

    const size_t direct_need = off + (size_t)N * DM * sizeof(int);
    const bool direct = direct_need <= ws_size;

    // CRITICAL ORDER: zero flag/cnt BEFORE detect_kernel runs (R3 crash was
    // this memset racing after detect in stream order, wiping the result).
    hipMemsetAsync(cnt, 0, (size_t)N * sizeof(int), stream);
    hipMemsetAsync(flag, 0, 16, stream);

    detect_kernel<<<1, 512, 0, stream>>>((const unsigned int*)adj, flag);
    gemm_kernel<<<(N + 255) / 256, 256, 0, stream>>>(x, W, xw, N);

    if (direct) {
        int* src2 = (int*)alloc((size_t)N * DM * sizeof(int));            // 51.2 MB
        fused_bucket_kernel<<<(E + 255) / 256, 256, 0, stream>>>(adj, flag, cnt, src2, E, N);
        gather_kernel<<<(N * 64 + 255) / 256, 256, 0, stream>>>(
            xw, nullptr, cnt, src2, b, out, N, DM);
    } else {
        const int NBLK = (N + SCAN_CHUNK - 1) / SCAN_CHUNK;
        int* starts = (int*)alloc((size_t)N * sizeof(int));
        int* cursor = (int*)alloc((size_t)N * sizeof(int));
        int* bsum   = (int*)alloc((size_t)NBLK * sizeof(int));
        int* src    = (int*)alloc((size_t)E * sizeof(int));
        degree_kernel<<<(E + 255) / 256, 256, 0, stream>>>(adj, flag, cnt, E, N);
        scan_partial_kernel<<<NBLK, 256, 0, stream>>>(cnt, bsum, N);
        scan_bsum_kernel<<<1, 64, 0, stream>>>(bsum, NBLK);
        scan_final_kernel<<<NBLK, 256, 0, stream>>>(cnt, bsum, starts, cursor, N);
        bucket_kernel<<<(E + 255) / 256, 256, 0, stream>>>(adj, flag, cursor, src, E, N);
        gather_kernel<<<(N * 64 + 255) / 256, 256, 0, stream>>>(
            xw, starts, cnt, src, b, out, N, 0);
    }
}

// Round 6
// 425.686 us; speedup vs baseline: 16.2713x; 1.4118x over previous
//
#include <hip/hip_runtime.h>

#define NFEAT 512
#define NCLS  40
#define SCAN_CHUNK 1024   // elements per scan block (256 threads x 4)
#define DM 128            // padded bucket width (legacy direct path)

// partition path parameters
#define NCB        256    // nodes per coarse bucket (c >> 8)
#define SLICE_CAP  80     // per (block,bucket) private slice capacity (mean 32)
#define P1B        256    // phase-1 block count
#define OVF_CAP    65536  // overflow ring capacity (virtually never used)

// ---------------------------------------------------------------------------
// Detect adj storage dtype. int64 (values < 2^31, LE) => odd 32-bit words all
// zero. int32 => odd words are random node ids. flag!=0 => int32.
// ---------------------------------------------------------------------------
__global__ void detect_kernel(const unsigned int* __restrict__ w,
                              unsigned int* __restrict__ flag) {
    unsigned int v = 0;
    for (int i = 1 + 2 * (int)threadIdx.x; i < 65536; i += 2 * (int)blockDim.x)
        v |= w[i];
    if (v) atomicOr(flag, 1u);
}

__device__ __forceinline__ void load_edge(const void* adj, int int32_mode,
                                          int e, int E, int& r, int& c) {
    if (int32_mode) {
        const int* a = (const int*)adj;
        r = a[e]; c = a[(size_t)E + e];
    } else {
        const long long* a = (const long long*)adj;
        r = (int)a[e]; c = (int)a[(size_t)E + e];
    }
}

// ---------------------------------------------------------------------------
// xw = x @ W^T   (N x 512) * (40 x 512)^T -> (N x 40)
// ---------------------------------------------------------------------------
__global__ void gemm_kernel(const float* __restrict__ x,
                            const float* __restrict__ W,
                            float* __restrict__ xw, int N) {
    int r = blockIdx.x * blockDim.x + threadIdx.x;
    if (r >= N) return;
    const float4* xr = reinterpret_cast<const float4*>(x) + (size_t)r * (NFEAT / 4);
    const float4* W4 = reinterpret_cast<const float4*>(W);
    float acc[NCLS];
#pragma unroll
    for (int c = 0; c < NCLS; ++c) acc[c] = 0.0f;
    for (int k4 = 0; k4 < NFEAT / 4; ++k4) {
        float4 xv = xr[k4];
#pragma unroll
        for (int c = 0; c < NCLS; ++c) {
            float4 wv = W4[c * (NFEAT / 4) + k4];   // thread-invariant -> scalarizable
            acc[c] = fmaf(xv.x, wv.x, acc[c]);
            acc[c] = fmaf(xv.y, wv.y, acc[c]);
            acc[c] = fmaf(xv.z, wv.z, acc[c]);
            acc[c] = fmaf(xv.w, wv.w, acc[c]);
        }
    }
    float4* o4 = reinterpret_cast<float4*>(xw + (size_t)r * NCLS);
#pragma unroll
    for (int j = 0; j < NCLS / 4; ++j)
        o4[j] = make_float4(acc[4 * j + 0], acc[4 * j + 1],
                            acc[4 * j + 2], acc[4 * j + 3]);
}

// ===========================================================================
// PARTITION PATH (no device-scope atomics; all scattered writes L2-local)
// ===========================================================================
// Phase 1: each of P1B blocks streams a contiguous edge chunk and appends
// (c&255, r) packed in 25 bits into its PRIVATE slice of bucket (c>>8).
// Cursors live in LDS; data writes are confined to ~125 KB per block.
__global__ void phase1_kernel(const void* __restrict__ adj,
                              const unsigned int* __restrict__ flag,
                              unsigned int* __restrict__ slices,
                              int* __restrict__ slice_cnt,
                              unsigned long long* __restrict__ ovf,
                              int* __restrict__ ovf_cnt,
                              int E, int N, int NB) {
    __shared__ int lcur[512];
    const int blk = blockIdx.x;
    for (int i = threadIdx.x; i < NB; i += blockDim.x) lcur[i] = 0;
    __syncthreads();
    const int m32 = *flag;
    const int chunk = (E + gridDim.x - 1) / gridDim.x;
    const int e0 = blk * chunk;
    const int e1 = min(E, e0 + chunk);
    for (int e = e0 + (int)threadIdx.x; e < e1; e += blockDim.x) {
        int r, c;
        load_edge(adj, m32, e, E, r, c);
        if (r == c) continue;
        if ((unsigned)r >= (unsigned)N || (unsigned)c >= (unsigned)N) continue;
        int b = c >> 8;
        unsigned int p = ((unsigned int)(c & 255) << 17) | (unsigned int)r;
        int pos = atomicAdd(&lcur[b], 1);            // LDS atomic
        if (pos < SLICE_CAP) {
            slices[((size_t)b * P1B + blk) * SLICE_CAP + pos] = p;
        } else {                                     // ~never (P < 1e-10)
            int oi = atomicAdd(ovf_cnt, 1);
            if (oi < OVF_CAP)
                ovf[oi] = ((unsigned long long)b << 32) | p;
        }
    }
    __syncthreads();
    for (int i = threadIdx.x; i < NB; i += blockDim.x)
        slice_cnt[(size_t)i * P1B + blk] = min(lcur[i], SLICE_CAP);
}

// Bucket totals: btot[b] = sum over slices + matching overflow entries.
__global__ void btot_kernel(const int* __restrict__ slice_cnt,
                            const unsigned long long* __restrict__ ovf,
                            const int* __restrict__ ovf_cnt,
                            int* __restrict__ btot, int NB) {
    __shared__ int sred[256];
    const int b = blockIdx.x;
    int s = 0;
    for (int i = threadIdx.x; i < P1B; i += blockDim.x)
        s += slice_cnt[(size_t)b * P1B + i];
    int no = min(*ovf_cnt, OVF_CAP);
    for (int i = threadIdx.x; i < no; i += blockDim.x)
        if ((int)(ovf[i] >> 32) == b) s++;
    sred[threadIdx.x] = s;
    __syncthreads();
    for (int o = 128; o > 0; o >>= 1) {
        if ((int)threadIdx.x < o) sred[threadIdx.x] += sred[threadIdx.x + o];
        __syncthreads();
    }
    if (threadIdx.x == 0) btot[b] = sred[0];
}

// Exclusive scan over NB (<=512) bucket totals; trivial serial.
__global__ void bscan_kernel(const int* __restrict__ btot,
                             int* __restrict__ bstart, int NB) {
    if (threadIdx.x == 0) {
        int a = 0;
        for (int i = 0; i < NB; ++i) { bstart[i] = a; a += btot[i]; }
    }
}

// Phase 2: one block per bucket. LDS histogram -> LDS scan -> compact CSR
// placement. All scattered writes confined to the bucket's ~33 KB src range.
__global__ void phase2_kernel(const unsigned int* __restrict__ slices,
                              const int* __restrict__ slice_cnt,
                              const unsigned long long* __restrict__ ovf,
                              const int* __restrict__ ovf_cnt,
                              const int* __restrict__ bstart,
                              int* __restrict__ starts,
                              int* __restrict__ cnt,
                              int* __restrict__ src, int N) {
    __shared__ int hist[NCB];
    __shared__ int lscan[NCB];
    __shared__ int cur[NCB];
    const int b = blockIdx.x;
    const int t = threadIdx.x;            // blockDim.x == 256 == NCB == P1B
    hist[t] = 0;
    __syncthreads();

    const int myk = slice_cnt[(size_t)b * P1B + t];   // thread t owns slice t
    const unsigned int* mysl = slices + ((size_t)b * P1B + t) * SLICE_CAP;
    for (int i = 0; i < myk; ++i)
        atomicAdd(&hist[mysl[i] >> 17], 1);
    const int no = min(*ovf_cnt, OVF_CAP);
    for (int i = t; i < no; i += 256)
        if ((int)(ovf[i] >> 32) == b)
            atomicAdd(&hist[((unsigned int)ovf[i]) >> 17], 1);
    __syncthreads();

    // exclusive scan of hist
    int h = hist[t];
    lscan[t] = h;
    __syncthreads();
    for (int o = 1; o < 256; o <<= 1) {
        int v = (t >= o) ? lscan[t - o] : 0;
        __syncthreads();
        lscan[t] += v;
        __syncthreads();
    }
    int excl = lscan[t] - h;
    cur[t] = excl;
    const int bs = bstart[b];
    const int c0 = b * NCB;
    if (c0 + t < N) {
        starts[c0 + t] = bs + excl;
        cnt[c0 + t] = h;
    }
    __syncthreads();

    for (int i = 0; i < myk; ++i) {
        unsigned int p = mysl[i];
        int pos = atomicAdd(&cur[p >> 17], 1);       // LDS atomic
        src[bs + pos] = (int)(p & 0x1FFFFu);
    }
    for (int i = t; i < no; i += 256) {
        if ((int)(ovf[i] >> 32) == b) {
            unsigned int p = (unsigned int)ovf[i];
            int pos = atomicAdd(&cur[p >> 17], 1);
            src[bs + pos] = (int)(p & 0x1FFFFu);
        }
    }
}

// ===========================================================================
// LEGACY DIRECT PATH (R4): single-pass rank placement, device atomics.
// ===========================================================================
__global__ void fused_bucket_kernel(const void* __restrict__ adj,
                                    const unsigned int* __restrict__ flag,
                                    int* __restrict__ cnt,
                                    int* __restrict__ src2, int E, int N) {
    int e = blockIdx.x * blockDim.x + threadIdx.x;
    if (e >= E) return;
    int r, c;
    load_edge(adj, *flag, e, E, r, c);
    if (r == c) return;
    if ((unsigned)r >= (unsigned)N || (unsigned)c >= (unsigned)N) return;
    int pos = atomicAdd(&cnt[c], 1);
    if (pos < DM) src2[(size_t)c * DM + pos] = r;
}

// ---------------------------------------------------------------------------
// Gather: one wave per node, lanes 0..39 own one class each.
// dm > 0: direct mode (start = wid*dm, d = min(cnt,dm)); dm == 0: CSR mode.
// ---------------------------------------------------------------------------
__global__ void gather_kernel(const float* __restrict__ xw,
                              const int* __restrict__ starts,
                              const int* __restrict__ deg,
                              const int* __restrict__ src,
                              const float* __restrict__ b,
                              float* __restrict__ out, int N, int dm) {
    int wid = (blockIdx.x * blockDim.x + threadIdx.x) >> 6;
    int lane = threadIdx.x & 63;
    if (wid >= N) return;
    int start, d;
    if (dm > 0) {
        start = wid * dm;
        d = __builtin_amdgcn_readfirstlane(min(deg[wid], dm));
    } else {
        start = __builtin_amdgcn_readfirstlane(starts[wid]);
        d = __builtin_amdgcn_readfirstlane(deg[wid]);
    }
    float scale = 1.0f / (float)(d + 1);
    bool act = lane < NCLS;
    const float* xwl = xw + lane;
    float acc = act ? xw[(size_t)wid * NCLS + lane] : 0.0f;
    const int* sp = src + start;
    int e = 0;
    for (; e + 8 <= d; e += 8) {
        int r0 = sp[e + 0], r1 = sp[e + 1], r2 = sp[e + 2], r3 = sp[e + 3];
        int r4 = sp[e + 4], r5 = sp[e + 5], r6 = sp[e + 6], r7 = sp[e + 7];
        float v0 = 0, v1 = 0, v2 = 0, v3 = 0, v4 = 0, v5 = 0, v6 = 0, v7 = 0;
        if (act) {
            v0 = xwl[(size_t)r0 * NCLS];
            v1 = xwl[(size_t)r1 * NCLS];
            v2 = xwl[(size_t)r2 * NCLS];
            v3 = xwl[(size_t)r3 * NCLS];
            v4 = xwl[(size_t)r4 * NCLS];
            v5 = xwl[(size_t)r5 * NCLS];
            v6 = xwl[(size_t)r6 * NCLS];
            v7 = xwl[(size_t)r7 * NCLS];
        }
        acc += ((v0 + v1) + (v2 + v3)) + ((v4 + v5) + (v6 + v7));
    }
    for (; e < d; ++e) {
        int r = sp[e];
        if (act) acc += xwl[(size_t)r * NCLS];
    }
    if (act) out[(size_t)wid * NCLS + lane] = fmaf(scale, acc, b[lane]);
}

extern "C" void kernel_launch(void* const* d_in, const int* in_sizes, int n_in,
                              void* d_out, int out_size, void* d_ws, size_t ws_size,
                              hipStream_t stream) {
    const float* x   = (const float*)d_in[0];
    const void*  adj = d_in[1];
    const float* W   = (const float*)d_in[2];
    const float* b   = (const float*)d_in[3];
    float* out = (float*)d_out;

    const int N = in_sizes[0] / NFEAT;   // 100000
    const int E = in_sizes[1] / 2;       // 3200000
    const int NB = (N + NCB - 1) / NCB;  // 391 coarse buckets

    char* ws = (char*)d_ws;
    size_t off = 0;
    auto alloc = [&](size_t bytes) { char* p = ws + off; off += (bytes + 15) & ~size_t(15); return p; };

    float* xw          = (float*)alloc((size_t)N * NCLS * sizeof(float)); // 16 MB
    int*   cnt         = (int*)  alloc((size_t)N * sizeof(int));
    unsigned int* flag = (unsigned int*)alloc(16);
    int*   ovf_cnt     = (int*)  alloc(16);

    // partition-path extra footprint
    const size_t part_need = off
        + (((size_t)NB * P1B * SLICE_CAP * 4 + 15) & ~size_t(15))   // slices ~32 MB
        + (((size_t)NB * P1B * 4 + 15) & ~size_t(15))               // slice_cnt 400 KB
        + 2 * (((size_t)NB * 4 + 15) & ~size_t(15))                 // btot, bstart
        + (((size_t)N * 4 + 15) & ~size_t(15))                      // starts
        + (((size_t)E * 4 + 15) & ~size_t(15))                      // src 12.8 MB
        + (size_t)OVF_CAP * 8;                                      // ovf ring
    const bool partition = (N <= 131072) && (NB <= 512) && (part_need <= ws_size);
    const size_t direct_need = off + (size_t)N * DM * sizeof(int);
    const bool direct = !partition && (direct_need <= ws_size);

    hipMemsetAsync(flag, 0, 32, stream);   // flag + ovf_cnt (adjacent 16B blocks)

    detect_kernel<<<1, 512, 0, stream>>>((const unsigned int*)adj, flag);
    gemm_kernel<<<(N + 255) / 256, 256, 0, stream>>>(x, W, xw, N);

    if (partition) {
        unsigned int* slices = (unsigned int*)alloc((size_t)NB * P1B * SLICE_CAP * 4);
        int* slice_cnt = (int*)alloc((size_t)NB * P1B * 4);
        int* btot   = (int*)alloc((size_t)NB * 4);
        int* bstart = (int*)alloc((size_t)NB * 4);
        int* starts = (int*)alloc((size_t)N * 4);
        int* src    = (int*)alloc((size_t)E * 4);
        unsigned long long* ovf = (unsigned long long*)alloc((size_t)OVF_CAP * 8);

        phase1_kernel<<<P1B, 256, 0, stream>>>(adj, flag, slices, slice_cnt,
                                               ovf, ovf_cnt, E, N, NB);
        btot_kernel<<<NB, 256, 0, stream>>>(slice_cnt, ovf, ovf_cnt, btot, NB);
        bscan_kernel<<<1, 64, 0, stream>>>(btot, bstart, NB);
        phase2_kernel<<<NB, 256, 0, stream>>>(slices, slice_cnt, ovf, ovf_cnt,
                                              bstart, starts, cnt, src, N);
        gather_kernel<<<(N * 64 + 255) / 256, 256, 0, stream>>>(
            xw, starts, cnt, src, b, out, N, 0);
    } else if (direct) {
        int* src2 = (int*)alloc((size_t)N * DM * sizeof(int));
        hipMemsetAsync(cnt, 0, (size_t)N * sizeof(int), stream);
        fused_bucket_kernel<<<(E + 255) / 256, 256, 0, stream>>>(adj, flag, cnt, src2, E, N);
        gather_kernel<<<(N * 64 + 255) / 256, 256, 0, stream>>>(
            xw, nullptr, cnt, src2, b, out, N, DM);
    }
    // (ws_size is known to cover one of the above paths on this harness)
}

// Round 7
// 292.176 us; speedup vs baseline: 23.7065x; 1.4570x over previous
//
#include <hip/hip_runtime.h>

#define NFEAT 512
#define NCLS  40
#define NPAD  48          // NCLS padded to 3 MFMA n-tiles of 16
#define DM 128            // padded bucket width (legacy direct path)

// partition path parameters
#define NCB        256    // nodes per coarse bucket (c >> 8)
#define SLICE_CAP  80     // per (block,bucket) private slice capacity (mean 32)
#define P1B        256    // phase-1 block count
#define OVF_CAP    65536  // overflow ring capacity (virtually never used)

typedef __attribute__((ext_vector_type(8))) short bf16x8;   // 8 bf16 (4 VGPRs)
typedef __attribute__((ext_vector_type(4))) float f32x4;

__device__ __forceinline__ unsigned short f2bf(float f) {   // RNE f32->bf16
    unsigned int u = __builtin_bit_cast(unsigned int, f);
    return (unsigned short)((u + 0x7FFFu + ((u >> 16) & 1u)) >> 16);
}

// ---------------------------------------------------------------------------
// Detect adj storage dtype. int64 (values < 2^31, LE) => odd 32-bit words all
// zero. int32 => odd words are random node ids. flag!=0 => int32.
// ---------------------------------------------------------------------------
__global__ void detect_kernel(const unsigned int* __restrict__ w,
                              unsigned int* __restrict__ flag) {
    unsigned int v = 0;
    for (int i = 1 + 2 * (int)threadIdx.x; i < 65536; i += 2 * (int)blockDim.x)
        v |= w[i];
    if (v) atomicOr(flag, 1u);
}

__device__ __forceinline__ void load_edge(const void* adj, int int32_mode,
                                          int e, int E, int& r, int& c) {
    if (int32_mode) {
        const int* a = (const int*)adj;
        r = a[e]; c = a[(size_t)E + e];
    } else {
        const long long* a = (const long long*)adj;
        r = (int)a[e]; c = (int)a[(size_t)E + e];
    }
}

// ---------------------------------------------------------------------------
// W [40][512] f32 -> Wb [48][512] bf16 (rows 40..47 zero).
// ---------------------------------------------------------------------------
__global__ void wconv_kernel(const float* __restrict__ W,
                             unsigned short* __restrict__ Wb) {
    int i = blockIdx.x * blockDim.x + threadIdx.x;
    if (i >= NPAD * NFEAT) return;
    int n = i >> 9;
    float v = (n < NCLS) ? W[i] : 0.0f;   // i == n*512+k and W is contiguous
    Wb[i] = f2bf(v);
}

// ---------------------------------------------------------------------------
// xw = x @ W^T via MFMA bf16. One wave per 16-row M-tile; 3 n-tiles (48 cols).
// A-frag: lane l -> row=l&15, k=(l>>4)*8..+7 (32B coalesced f32 load + cvt).
// B-frag: W is [N][K] row-major == B^T input; same pattern as A.
// C/D: col=lane&15, row=(lane>>4)*4+reg  [verified mapping].
// ---------------------------------------------------------------------------
__global__ __launch_bounds__(256) void gemm_mfma_kernel(
        const float* __restrict__ x, const unsigned short* __restrict__ Wb,
        float* __restrict__ xw, int N) {
    int wid  = (blockIdx.x * blockDim.x + threadIdx.x) >> 6;  // m-tile index
    int lane = threadIdx.x & 63;
    if (wid * 16 >= N) return;
    int row = lane & 15;
    int ks  = lane >> 4;                                      // 0..3
    const float*          xrow = x  + (size_t)(wid * 16 + row) * NFEAT + ks * 8;
    const unsigned short* wb0  = Wb + (size_t)row * NFEAT + ks * 8;      // n-tile 0
    const unsigned short* wb1  = wb0 + (size_t)16 * NFEAT;               // n-tile 1
    const unsigned short* wb2  = wb0 + (size_t)32 * NFEAT;               // n-tile 2

    f32x4 acc0 = {0.f, 0.f, 0.f, 0.f};
    f32x4 acc1 = {0.f, 0.f, 0.f, 0.f};
    f32x4 acc2 = {0.f, 0.f, 0.f, 0.f};

    for (int kk = 0; kk < NFEAT; kk += 32) {
        float4 xa = *reinterpret_cast<const float4*>(xrow + kk);
        float4 xb = *reinterpret_cast<const float4*>(xrow + kk + 4);
        bf16x8 a;
        a[0] = (short)f2bf(xa.x); a[1] = (short)f2bf(xa.y);
        a[2] = (short)f2bf(xa.z); a[3] = (short)f2bf(xa.w);
        a[4] = (short)f2bf(xb.x); a[5] = (short)f2bf(xb.y);
        a[6] = (short)f2bf(xb.z); a[7] = (short)f2bf(xb.w);
        bf16x8 b0 = *reinterpret_cast<const bf16x8*>(wb0 + kk);
        bf16x8 b1 = *reinterpret_cast<const bf16x8*>(wb1 + kk);
        bf16x8 b2 = *reinterpret_cast<const bf16x8*>(wb2 + kk);
        acc0 = __builtin_amdgcn_mfma_f32_16x16x32_bf16(a, b0, acc0, 0, 0, 0);
        acc1 = __builtin_amdgcn_mfma_f32_16x16x32_bf16(a, b1, acc1, 0, 0, 0);
        acc2 = __builtin_amdgcn_mfma_f32_16x16x32_bf16(a, b2, acc2, 0, 0, 0);
    }

    int crow = wid * 16 + ks * 4;   // + reg
    int ccol = row;
#pragma unroll
    for (int i = 0; i < 4; ++i) {
        float* orow = xw + (size_t)(crow + i) * NCLS;
        orow[ccol]      = acc0[i];
        orow[16 + ccol] = acc1[i];
        if (ccol < 8) orow[32 + ccol] = acc2[i];   // cols 40..47 are padding
    }
}

// ===========================================================================
// PARTITION PATH (no device-scope atomics; all scattered writes L2-local)
// ===========================================================================
__global__ void phase1_kernel(const void* __restrict__ adj,
                              const unsigned int* __restrict__ flag,
                              unsigned int* __restrict__ slices,
                              int* __restrict__ slice_cnt,
                              unsigned long long* __restrict__ ovf,
                              int* __restrict__ ovf_cnt,
                              int E, int N, int NB) {
    __shared__ int lcur[512];
    const int blk = blockIdx.x;
    for (int i = threadIdx.x; i < NB; i += blockDim.x) lcur[i] = 0;
    __syncthreads();
    const int m32 = *flag;
    const int chunk = (E + gridDim.x - 1) / gridDim.x;
    const int e0 = blk * chunk;
    const int e1 = min(E, e0 + chunk);
    for (int e = e0 + (int)threadIdx.x; e < e1; e += blockDim.x) {
        int r, c;
        load_edge(adj, m32, e, E, r, c);
        if (r == c) continue;
        if ((unsigned)r >= (unsigned)N || (unsigned)c >= (unsigned)N) continue;
        int b = c >> 8;
        unsigned int p = ((unsigned int)(c & 255) << 17) | (unsigned int)r;
        int pos = atomicAdd(&lcur[b], 1);            // LDS atomic
        if (pos < SLICE_CAP) {
            slices[((size_t)b * P1B + blk) * SLICE_CAP + pos] = p;
        } else {
            int oi = atomicAdd(ovf_cnt, 1);
            if (oi < OVF_CAP)
                ovf[oi] = ((unsigned long long)b << 32) | p;
        }
    }
    __syncthreads();
    for (int i = threadIdx.x; i < NB; i += blockDim.x)
        slice_cnt[(size_t)i * P1B + blk] = min(lcur[i], SLICE_CAP);
}

__global__ void btot_kernel(const int* __restrict__ slice_cnt,
                            const unsigned long long* __restrict__ ovf,
                            const int* __restrict__ ovf_cnt,
                            int* __restrict__ btot, int NB) {
    __shared__ int sred[256];
    const int b = blockIdx.x;
    int s = 0;
    for (int i = threadIdx.x; i < P1B; i += blockDim.x)
        s += slice_cnt[(size_t)b * P1B + i];
    int no = min(*ovf_cnt, OVF_CAP);
    for (int i = threadIdx.x; i < no; i += blockDim.x)
        if ((int)(ovf[i] >> 32) == b) s++;
    sred[threadIdx.x] = s;
    __syncthreads();
    for (int o = 128; o > 0; o >>= 1) {
        if ((int)threadIdx.x < o) sred[threadIdx.x] += sred[threadIdx.x + o];
        __syncthreads();
    }
    if (threadIdx.x == 0) btot[b] = sred[0];
}

__global__ void bscan_kernel(const int* __restrict__ btot,
                             int* __restrict__ bstart, int NB) {
    if (threadIdx.x == 0) {
        int a = 0;
        for (int i = 0; i < NB; ++i) { bstart[i] = a; a += btot[i]; }
    }
}

__global__ void phase2_kernel(const unsigned int* __restrict__ slices,
                              const int* __restrict__ slice_cnt,
                              const unsigned long long* __restrict__ ovf,
                              const int* __restrict__ ovf_cnt,
                              const int* __restrict__ bstart,
                              int* __restrict__ starts,
                              int* __restrict__ cnt,
                              int* __restrict__ src, int N) {
    __shared__ int hist[NCB];
    __shared__ int lscan[NCB];
    __shared__ int cur[NCB];
    const int b = blockIdx.x;
    const int t = threadIdx.x;            // blockDim.x == 256 == NCB == P1B
    hist[t] = 0;
    __syncthreads();

    const int myk = slice_cnt[(size_t)b * P1B + t];
    const unsigned int* mysl = slices + ((size_t)b * P1B + t) * SLICE_CAP;
    for (int i = 0; i < myk; ++i)
        atomicAdd(&hist[mysl[i] >> 17], 1);
    const int no = min(*ovf_cnt, OVF_CAP);
    for (int i = t; i < no; i += 256)
        if ((int)(ovf[i] >> 32) == b)
            atomicAdd(&hist[((unsigned int)ovf[i]) >> 17], 1);
    __syncthreads();

    int h = hist[t];
    lscan[t] = h;
    __syncthreads();
    for (int o = 1; o < 256; o <<= 1) {
        int v = (t >= o) ? lscan[t - o] : 0;
        __syncthreads();
        lscan[t] += v;
        __syncthreads();
    }
    int excl = lscan[t] - h;
    cur[t] = excl;
    const int bs = bstart[b];
    const int c0 = b * NCB;
    if (c0 + t < N) {
        starts[c0 + t] = bs + excl;
        cnt[c0 + t] = h;
    }
    __syncthreads();

    for (int i = 0; i < myk; ++i) {
        unsigned int p = mysl[i];
        int pos = atomicAdd(&cur[p >> 17], 1);       // LDS atomic
        src[bs + pos] = (int)(p & 0x1FFFFu);
    }
    for (int i = t; i < no; i += 256) {
        if ((int)(ovf[i] >> 32) == b) {
            unsigned int p = (unsigned int)ovf[i];
            int pos = atomicAdd(&cur[p >> 17], 1);
            src[bs + pos] = (int)(p & 0x1FFFFu);
        }
    }
}

// ===========================================================================
// LEGACY DIRECT PATH: single-pass rank placement, device atomics.
// ===========================================================================
__global__ void fused_bucket_kernel(const void* __restrict__ adj,
                                    const unsigned int* __restrict__ flag,
                                    int* __restrict__ cnt,
                                    int* __restrict__ src2, int E, int N) {
    int e = blockIdx.x * blockDim.x + threadIdx.x;
    if (e >= E) return;
    int r, c;
    load_edge(adj, *flag, e, E, r, c);
    if (r == c) return;
    if ((unsigned)r >= (unsigned)N || (unsigned)c >= (unsigned)N) return;
    int pos = atomicAdd(&cnt[c], 1);
    if (pos < DM) src2[(size_t)c * DM + pos] = r;
}

// ---------------------------------------------------------------------------
// Gather: one wave per node, lanes 0..39 own one class each.
// dm > 0: direct mode; dm == 0: CSR mode.
// ---------------------------------------------------------------------------
__global__ void gather_kernel(const float* __restrict__ xw,
                              const int* __restrict__ starts,
                              const int* __restrict__ deg,
                              const int* __restrict__ src,
                              const float* __restrict__ b,
                              float* __restrict__ out, int N, int dm) {
    int wid = (blockIdx.x * blockDim.x + threadIdx.x) >> 6;
    int lane = threadIdx.x & 63;
    if (wid >= N) return;
    int start, d;
    if (dm > 0) {
        start = wid * dm;
        d = __builtin_amdgcn_readfirstlane(min(deg[wid], dm));
    } else {
        start = __builtin_amdgcn_readfirstlane(starts[wid]);
        d = __builtin_amdgcn_readfirstlane(deg[wid]);
    }
    float scale = 1.0f / (float)(d + 1);
    bool act = lane < NCLS;
    const float* xwl = xw + lane;
    float acc = act ? xw[(size_t)wid * NCLS + lane] : 0.0f;
    const int* sp = src + start;
    int e = 0;
    for (; e + 8 <= d; e += 8) {
        int r0 = sp[e + 0], r1 = sp[e + 1], r2 = sp[e + 2], r3 = sp[e + 3];
        int r4 = sp[e + 4], r5 = sp[e + 5], r6 = sp[e + 6], r7 = sp[e + 7];
        float v0 = 0, v1 = 0, v2 = 0, v3 = 0, v4 = 0, v5 = 0, v6 = 0, v7 = 0;
        if (act) {
            v0 = xwl[(size_t)r0 * NCLS];
            v1 = xwl[(size_t)r1 * NCLS];
            v2 = xwl[(size_t)r2 * NCLS];
            v3 = xwl[(size_t)r3 * NCLS];
            v4 = xwl[(size_t)r4 * NCLS];
            v5 = xwl[(size_t)r5 * NCLS];
            v6 = xwl[(size_t)r6 * NCLS];
            v7 = xwl[(size_t)r7 * NCLS];
        }
        acc += ((v0 + v1) + (v2 + v3)) + ((v4 + v5) + (v6 + v7));
    }
    for (; e < d; ++e) {
        int r = sp[e];
        if (act) acc += xwl[(size_t)r * NCLS];
    }
    if (act) out[(size_t)wid * NCLS + lane] = fmaf(scale, acc, b[lane]);
}

extern "C" void kernel_launch(void* const* d_in, const int* in_sizes, int n_in,
                              void* d_out, int out_size, void* d_ws, size_t ws_size,
                              hipStream_t stream) {
    const float* x   = (const float*)d_in[0];
    const void*  adj = d_in[1];
    const float* W   = (const float*)d_in[2];
    const float* b   = (const float*)d_in[3];
    float* out = (float*)d_out;

    const int N = in_sizes[0] / NFEAT;   // 100000
    const int E = in_sizes[1] / 2;       // 3200000
    const int NB = (N + NCB - 1) / NCB;  // 391 coarse buckets

    char* ws = (char*)d_ws;
    size_t off = 0;
    auto alloc = [&](size_t bytes) { char* p = ws + off; off += (bytes + 15) & ~size_t(15); return p; };

    float* xw          = (float*)alloc((size_t)N * NCLS * sizeof(float)); // 16 MB
    int*   cnt         = (int*)  alloc((size_t)N * sizeof(int));
    unsigned int* flag = (unsigned int*)alloc(16);
    int*   ovf_cnt     = (int*)  alloc(16);
    unsigned short* Wb = (unsigned short*)alloc((size_t)NPAD * NFEAT * 2); // 48 KB

    const size_t part_need = off
        + (((size_t)NB * P1B * SLICE_CAP * 4 + 15) & ~size_t(15))   // slices ~32 MB
        + (((size_t)NB * P1B * 4 + 15) & ~size_t(15))               // slice_cnt
        + 2 * (((size_t)NB * 4 + 15) & ~size_t(15))                 // btot, bstart
        + (((size_t)N * 4 + 15) & ~size_t(15))                      // starts
        + (((size_t)E * 4 + 15) & ~size_t(15))                      // src 12.8 MB
        + (size_t)OVF_CAP * 8;                                      // ovf ring
    const bool partition = (N <= 131072) && (NB <= 512) && (part_need <= ws_size);
    const size_t direct_need = off + (size_t)N * DM * sizeof(int);
    const bool direct = !partition && (direct_need <= ws_size);

    hipMemsetAsync(flag, 0, 32, stream);   // flag + ovf_cnt

    detect_kernel<<<1, 512, 0, stream>>>((const unsigned int*)adj, flag);
    wconv_kernel<<<(NPAD * NFEAT + 255) / 256, 256, 0, stream>>>(W, Wb);
    gemm_mfma_kernel<<<((N + 15) / 16 + 3) / 4, 256, 0, stream>>>(x, Wb, xw, N);

    if (partition) {
        unsigned int* slices = (unsigned int*)alloc((size_t)NB * P1B * SLICE_CAP * 4);
        int* slice_cnt = (int*)alloc((size_t)NB * P1B * 4);
        int* btot   = (int*)alloc((size_t)NB * 4);
        int* bstart = (int*)alloc((size_t)NB * 4);
        int* starts = (int*)alloc((size_t)N * 4);
        int* src    = (int*)alloc((size_t)E * 4);
        unsigned long long* ovf = (unsigned long long*)alloc((size_t)OVF_CAP * 8);

        phase1_kernel<<<P1B, 256, 0, stream>>>(adj, flag, slices, slice_cnt,
                                               ovf, ovf_cnt, E, N, NB);
        btot_kernel<<<NB, 256, 0, stream>>>(slice_cnt, ovf, ovf_cnt, btot, NB);
        bscan_kernel<<<1, 64, 0, stream>>>(btot, bstart, NB);
        phase2_kernel<<<NB, 256, 0, stream>>>(slices, slice_cnt, ovf, ovf_cnt,
                                              bstart, starts, cnt, src, N);
        gather_kernel<<<(N * 64 + 255) / 256, 256, 0, stream>>>(
            xw, starts, cnt, src, b, out, N, 0);
    } else if (direct) {
        int* src2 = (int*)alloc((size_t)N * DM * sizeof(int));
        hipMemsetAsync(cnt, 0, (size_t)N * sizeof(int), stream);
        fused_bucket_kernel<<<(E + 255) / 256, 256, 0, stream>>>(adj, flag, cnt, src2, E, N);
        gather_kernel<<<(N * 64 + 255) / 256, 256, 0, stream>>>(
            xw, nullptr, cnt, src2, b, out, N, DM);
    }
}

// Round 8
// 258.284 us; speedup vs baseline: 26.8173x; 1.1312x over previous
//
#include <hip/hip_runtime.h>

#define NFEAT 512
#define NCLS  40
#define NPAD  48          // NCLS padded to 3 MFMA n-tiles of 16
#define DM 128            // padded bucket width (legacy direct path)

// partition path parameters
#define NCB        256    // nodes per coarse bucket (c >> 8)
#define SLICE_CAP  80     // per (block,bucket) private slice capacity (mean 32)
#define P1B        256    // phase-1 block count
#define BCAP       16384  // fixed src region per bucket (mean 8192)
#define OVF_CAP    65536  // overflow ring capacity (virtually never used)

typedef __attribute__((ext_vector_type(8))) short bf16x8;   // 8 bf16 (4 VGPRs)
typedef __attribute__((ext_vector_type(4))) float f32x4;

__device__ __forceinline__ unsigned short f2bf(float f) {   // RNE f32->bf16
    unsigned int u = __builtin_bit_cast(unsigned int, f);
    return (unsigned short)((u + 0x7FFFu + ((u >> 16) & 1u)) >> 16);
}
__device__ __forceinline__ float bf2f(unsigned short h) {
    return __builtin_bit_cast(float, (unsigned int)h << 16);
}

__device__ __forceinline__ void load_edge(const void* adj, int int32_mode,
                                          int e, int E, int& r, int& c) {
    if (int32_mode) {
        const int* a = (const int*)adj;
        r = a[e]; c = a[(size_t)E + e];
    } else {
        const long long* a = (const long long*)adj;
        r = (int)a[e]; c = (int)a[(size_t)E + e];
    }
}

// ---------------------------------------------------------------------------
// W [40][512] f32 -> Wb [48][512] bf16 (rows 40..47 zero).
// ---------------------------------------------------------------------------
__global__ void wconv_kernel(const float* __restrict__ W,
                             unsigned short* __restrict__ Wb) {
    int i = blockIdx.x * blockDim.x + threadIdx.x;
    if (i >= NPAD * NFEAT) return;
    int n = i >> 9;
    float v = (n < NCLS) ? W[i] : 0.0f;
    Wb[i] = f2bf(v);
}

// ===========================================================================
// FUSED: blocks [0, P1B) run edge-partition phase 1; blocks [P1B, ...) run
// the MFMA GEMM. Independent work co-scheduled in one launch; phase-1 blocks
// first so they start immediately and overlap the gemm wavefront.
// ===========================================================================
__global__ __launch_bounds__(256) void fused_gemm_phase1(
        const float* __restrict__ x, const unsigned short* __restrict__ Wb,
        unsigned short* __restrict__ xwb, const void* __restrict__ adj,
        unsigned int* __restrict__ slices, int* __restrict__ slice_cnt,
        unsigned long long* __restrict__ ovf, int* __restrict__ ovf_cnt,
        int N, int E, int NB) {
    __shared__ int lcur[512];
    __shared__ unsigned int det;

    if (blockIdx.x < P1B) {
        // ----- phase 1: private-slice edge partition (LDS cursors) -----
        const int blk = blockIdx.x;
        for (int i = threadIdx.x; i < NB; i += 256) lcur[i] = 0;
        if (threadIdx.x == 0) det = 0u;
        __syncthreads();
        // inline dtype detect: odd 32-bit words all-zero <=> int64 storage
        const unsigned int* aw = (const unsigned int*)adj;
        unsigned int v = aw[2 * threadIdx.x + 1] | aw[2 * (threadIdx.x + 256) + 1];
        if (v) atomicOr(&det, 1u);
        __syncthreads();
        const int m32 = (det != 0);
        const int chunk = (E + P1B - 1) / P1B;
        const int e0 = blk * chunk;
        const int e1 = min(E, e0 + chunk);
        for (int e = e0 + (int)threadIdx.x; e < e1; e += 256) {
            int r, c;
            load_edge(adj, m32, e, E, r, c);
            if (r == c) continue;
            if ((unsigned)r >= (unsigned)N || (unsigned)c >= (unsigned)N) continue;
            int b = c >> 8;
            unsigned int p = ((unsigned int)(c & 255) << 17) | (unsigned int)r;
            int pos = atomicAdd(&lcur[b], 1);            // LDS atomic
            if (pos < SLICE_CAP) {
                slices[((size_t)b * P1B + blk) * SLICE_CAP + pos] = p;
            } else {
                int oi = atomicAdd(ovf_cnt, 1);
                if (oi < OVF_CAP)
                    ovf[oi] = ((unsigned long long)b << 32) | p;
            }
        }
        __syncthreads();
        for (int i = threadIdx.x; i < NB; i += 256)
            slice_cnt[(size_t)i * P1B + blk] = min(lcur[i], SLICE_CAP);
        return;
    }

    // ----- gemm role: xw = x @ W^T via mfma_f32_16x16x32_bf16 -----
    int wid  = (int)(blockIdx.x - P1B) * 4 + ((int)threadIdx.x >> 6);
    int lane = threadIdx.x & 63;
    int m0 = wid * 16;
    if (m0 >= N) return;
    int row = lane & 15;
    int ks  = lane >> 4;                                      // 0..3
    int arow = min(m0 + row, N - 1);
    const float*          xrow = x  + (size_t)arow * NFEAT + ks * 8;
    const unsigned short* wb0  = Wb + (size_t)row * NFEAT + ks * 8;
    const unsigned short* wb1  = wb0 + (size_t)16 * NFEAT;
    const unsigned short* wb2  = wb0 + (size_t)32 * NFEAT;

    f32x4 acc0 = {0.f, 0.f, 0.f, 0.f};
    f32x4 acc1 = {0.f, 0.f, 0.f, 0.f};
    f32x4 acc2 = {0.f, 0.f, 0.f, 0.f};

    for (int kk = 0; kk < NFEAT; kk += 32) {
        float4 xa = *reinterpret_cast<const float4*>(xrow + kk);
        float4 xb = *reinterpret_cast<const float4*>(xrow + kk + 4);
        bf16x8 a;
        a[0] = (short)f2bf(xa.x); a[1] = (short)f2bf(xa.y);
        a[2] = (short)f2bf(xa.z); a[3] = (short)f2bf(xa.w);
        a[4] = (short)f2bf(xb.x); a[5] = (short)f2bf(xb.y);
        a[6] = (short)f2bf(xb.z); a[7] = (short)f2bf(xb.w);
        bf16x8 b0 = *reinterpret_cast<const bf16x8*>(wb0 + kk);
        bf16x8 b1 = *reinterpret_cast<const bf16x8*>(wb1 + kk);
        bf16x8 b2 = *reinterpret_cast<const bf16x8*>(wb2 + kk);
        acc0 = __builtin_amdgcn_mfma_f32_16x16x32_bf16(a, b0, acc0, 0, 0, 0);
        acc1 = __builtin_amdgcn_mfma_f32_16x16x32_bf16(a, b1, acc1, 0, 0, 0);
        acc2 = __builtin_amdgcn_mfma_f32_16x16x32_bf16(a, b2, acc2, 0, 0, 0);
    }

    int ccol = row;
#pragma unroll
    for (int i = 0; i < 4; ++i) {
        int crow = m0 + ks * 4 + i;
        if (crow < N) {
            unsigned short* orow = xwb + (size_t)crow * NCLS;
            orow[ccol]      = f2bf(acc0[i]);
            orow[16 + ccol] = f2bf(acc1[i]);
            if (ccol < 8) orow[32 + ccol] = f2bf(acc2[i]);
        }
    }
}

// ---------------------------------------------------------------------------
// Phase 2: one block per bucket; fixed region bs = b*BCAP (no scan kernels).
// LDS histogram -> LDS exclusive scan -> compact placement + starts/cnt.
// ---------------------------------------------------------------------------
__global__ void phase2_kernel(const unsigned int* __restrict__ slices,
                              const int* __restrict__ slice_cnt,
                              const unsigned long long* __restrict__ ovf,
                              const int* __restrict__ ovf_cnt,
                              int* __restrict__ starts,
                              int* __restrict__ cnt,
                              int* __restrict__ src, int N) {
    __shared__ int hist[NCB];
    __shared__ int lscan[NCB];
    __shared__ int cur[NCB];
    const int b = blockIdx.x;
    const int t = threadIdx.x;            // blockDim.x == 256 == NCB == P1B
    hist[t] = 0;
    __syncthreads();

    const int myk = slice_cnt[(size_t)b * P1B + t];   // thread t owns slice t
    const unsigned int* mysl = slices + ((size_t)b * P1B + t) * SLICE_CAP;
    for (int i = 0; i < myk; ++i)
        atomicAdd(&hist[mysl[i] >> 17], 1);
    const int no = min(*ovf_cnt, OVF_CAP);
    for (int i = t; i < no; i += 256)
        if ((int)(ovf[i] >> 32) == b)
            atomicAdd(&hist[((unsigned int)ovf[i]) >> 17], 1);
    __syncthreads();

    int h = hist[t];
    lscan[t] = h;
    __syncthreads();
    for (int o = 1; o < 256; o <<= 1) {
        int v = (t >= o) ? lscan[t - o] : 0;
        __syncthreads();
        lscan[t] += v;
        __syncthreads();
    }
    int excl = lscan[t] - h;
    cur[t] = excl;
    const int bs = b * BCAP;
    const int c0 = b * NCB;
    if (c0 + t < N) {
        starts[c0 + t] = bs + excl;
        cnt[c0 + t] = h;
    }
    __syncthreads();

    for (int i = 0; i < myk; ++i) {
        unsigned int p = mysl[i];
        int pos = atomicAdd(&cur[p >> 17], 1);       // LDS atomic
        if (pos < BCAP) src[bs + pos] = (int)(p & 0x1FFFFu);
    }
    for (int i = t; i < no; i += 256) {
        if ((int)(ovf[i] >> 32) == b) {
            unsigned int p = (unsigned int)ovf[i];
            int pos = atomicAdd(&cur[p >> 17], 1);
            if (pos < BCAP) src[bs + pos] = (int)(p & 0x1FFFFu);
        }
    }
}

// ===========================================================================
// LEGACY DIRECT PATH (fallback only): device-atomic rank placement.
// ===========================================================================
__global__ void detect_kernel(const unsigned int* __restrict__ w,
                              unsigned int* __restrict__ flag) {
    unsigned int v = 0;
    for (int i = 1 + 2 * (int)threadIdx.x; i < 65536; i += 2 * (int)blockDim.x)
        v |= w[i];
    if (v) atomicOr(flag, 1u);
}

__global__ void fused_bucket_kernel(const void* __restrict__ adj,
                                    const unsigned int* __restrict__ flag,
                                    int* __restrict__ cnt,
                                    int* __restrict__ src2, int E, int N) {
    int e = blockIdx.x * blockDim.x + threadIdx.x;
    if (e >= E) return;
    int r, c;
    load_edge(adj, *flag, e, E, r, c);
    if (r == c) return;
    if ((unsigned)r >= (unsigned)N || (unsigned)c >= (unsigned)N) return;
    int pos = atomicAdd(&cnt[c], 1);
    if (pos < DM) src2[(size_t)c * DM + pos] = r;
}

// legacy gemm writing bf16 (fallback path uses it too via fused kernel's role)
// ---------------------------------------------------------------------------
// Gather: one wave per node, lanes 0..39 own one class each; bf16 xw rows.
// dm > 0: direct mode; dm == 0: CSR mode.
// ---------------------------------------------------------------------------
__global__ void gather_kernel(const unsigned short* __restrict__ xwb,
                              const int* __restrict__ starts,
                              const int* __restrict__ deg,
                              const int* __restrict__ src,
                              const float* __restrict__ b,
                              float* __restrict__ out, int N, int dm) {
    int wid = (blockIdx.x * blockDim.x + threadIdx.x) >> 6;
    int lane = threadIdx.x & 63;
    if (wid >= N) return;
    int start, d;
    if (dm > 0) {
        start = wid * dm;
        d = __builtin_amdgcn_readfirstlane(min(deg[wid], dm));
    } else {
        start = __builtin_amdgcn_readfirstlane(starts[wid]);
        d = __builtin_amdgcn_readfirstlane(deg[wid]);
    }
    float scale = 1.0f / (float)(d + 1);
    bool act = lane < NCLS;
    const unsigned short* xwl = xwb + lane;
    float acc = act ? bf2f(xwb[(size_t)wid * NCLS + lane]) : 0.0f;
    const int* sp = src + start;
    int e = 0;
    for (; e + 8 <= d; e += 8) {
        int r0 = sp[e + 0], r1 = sp[e + 1], r2 = sp[e + 2], r3 = sp[e + 3];
        int r4 = sp[e + 4], r5 = sp[e + 5], r6 = sp[e + 6], r7 = sp[e + 7];
        float v0 = 0, v1 = 0, v2 = 0, v3 = 0, v4 = 0, v5 = 0, v6 = 0, v7 = 0;
        if (act) {
            v0 = bf2f(xwl[(size_t)r0 * NCLS]);
            v1 = bf2f(xwl[(size_t)r1 * NCLS]);
            v2 = bf2f(xwl[(size_t)r2 * NCLS]);
            v3 = bf2f(xwl[(size_t)r3 * NCLS]);
            v4 = bf2f(xwl[(size_t)r4 * NCLS]);
            v5 = bf2f(xwl[(size_t)r5 * NCLS]);
            v6 = bf2f(xwl[(size_t)r6 * NCLS]);
            v7 = bf2f(xwl[(size_t)r7 * NCLS]);
        }
        acc += ((v0 + v1) + (v2 + v3)) + ((v4 + v5) + (v6 + v7));
    }
    for (; e < d; ++e) {
        int r = sp[e];
        if (act) acc += bf2f(xwl[(size_t)r * NCLS]);
    }
    if (act) out[(size_t)wid * NCLS + lane] = fmaf(scale, acc, b[lane]);
}

extern "C" void kernel_launch(void* const* d_in, const int* in_sizes, int n_in,
                              void* d_out, int out_size, void* d_ws, size_t ws_size,
                              hipStream_t stream) {
    const float* x   = (const float*)d_in[0];
    const void*  adj = d_in[1];
    const float* W   = (const float*)d_in[2];
    const float* b   = (const float*)d_in[3];
    float* out = (float*)d_out;

    const int N = in_sizes[0] / NFEAT;   // 100000
    const int E = in_sizes[1] / 2;       // 3200000
    const int NB = (N + NCB - 1) / NCB;  // 391 coarse buckets
    const int GEMMB = (N + 63) / 64;     // 4 m-tiles of 16 rows per block

    char* ws = (char*)d_ws;
    size_t off = 0;
    auto alloc = [&](size_t bytes) { char* p = ws + off; off += (bytes + 15) & ~size_t(15); return p; };

    unsigned short* xwb = (unsigned short*)alloc((size_t)N * NCLS * 2);   // 8 MB
    int*   cnt          = (int*)  alloc((size_t)N * sizeof(int));
    unsigned int* flag  = (unsigned int*)alloc(16);
    int*   ovf_cnt      = (int*)  alloc(16);
    unsigned short* Wb  = (unsigned short*)alloc((size_t)NPAD * NFEAT * 2);

    const size_t part_need = off
        + (((size_t)NB * P1B * SLICE_CAP * 4 + 15) & ~size_t(15))   // slices ~32 MB
        + (((size_t)NB * P1B * 4 + 15) & ~size_t(15))               // slice_cnt
        + (((size_t)N * 4 + 15) & ~size_t(15))                      // starts
        + (((size_t)NB * BCAP * 4 + 15) & ~size_t(15))              // src 25.6 MB
        + (size_t)OVF_CAP * 8;                                      // ovf ring
    const bool partition = (N <= NCB * 512) && (NB <= 512) && (E >= 512)
                           && (part_need <= ws_size);
    const size_t direct_need = off + (size_t)N * DM * sizeof(int);
    const bool direct = !partition && (direct_need <= ws_size);

    hipMemsetAsync(flag, 0, 32, stream);   // flag + ovf_cnt
    wconv_kernel<<<(NPAD * NFEAT + 255) / 256, 256, 0, stream>>>(W, Wb);

    if (partition) {
        unsigned int* slices = (unsigned int*)alloc((size_t)NB * P1B * SLICE_CAP * 4);
        int* slice_cnt = (int*)alloc((size_t)NB * P1B * 4);
        int* starts = (int*)alloc((size_t)N * 4);
        int* src    = (int*)alloc((size_t)NB * BCAP * 4);
        unsigned long long* ovf = (unsigned long long*)alloc((size_t)OVF_CAP * 8);

        fused_gemm_phase1<<<P1B + GEMMB, 256, 0, stream>>>(
            x, Wb, xwb, adj, slices, slice_cnt, ovf, ovf_cnt, N, E, NB);
        phase2_kernel<<<NB, 256, 0, stream>>>(slices, slice_cnt, ovf, ovf_cnt,
                                              starts, cnt, src, N);
        gather_kernel<<<(N * 64 + 255) / 256, 256, 0, stream>>>(
            xwb, starts, cnt, src, b, out, N, 0);
    } else if (direct) {
        int* src2 = (int*)alloc((size_t)N * DM * sizeof(int));
        hipMemsetAsync(cnt, 0, (size_t)N * sizeof(int), stream);
        detect_kernel<<<1, 512, 0, stream>>>((const unsigned int*)adj, flag);
        // reuse fused kernel's gemm role only (grid offset by P1B)
        fused_gemm_phase1<<<P1B + GEMMB, 256, 0, stream>>>(
            x, Wb, xwb, adj, nullptr, nullptr, nullptr, ovf_cnt, N, 0, NB);
        fused_bucket_kernel<<<(E + 255) / 256, 256, 0, stream>>>(adj, flag, cnt, src2, E, N);
        gather_kernel<<<(N * 64 + 255) / 256, 256, 0, stream>>>(
            xwb, nullptr, cnt, src2, b, out, N, DM);
    }
}

// Round 9
// 238.729 us; speedup vs baseline: 29.0139x; 1.0819x over previous
//
#include <hip/hip_runtime.h>

#define NFEAT 512
#define NCLS  40
#define NPAD  48          // NCLS padded to 3 MFMA n-tiles of 16
#define DM 128            // padded bucket width (legacy direct path)

// partition path parameters
#define NCB        256    // nodes per coarse bucket (c >> 8)
#define SLICE_CAP  80     // per (block,bucket) private slice capacity (mean 32)
#define P1B        256    // phase-1 block count
#define BCAP       16384  // fixed src region per bucket (mean 8192)
#define OVF_CAP    65536  // overflow ring capacity (virtually never used)

#define XSC 520           // LDS tile cols (512 + 8 pad, bf16)

typedef __attribute__((ext_vector_type(8))) short bf16x8;   // 8 bf16 (4 VGPRs)
typedef __attribute__((ext_vector_type(4))) float f32x4;

__device__ __forceinline__ unsigned short f2bf(float f) {   // RNE f32->bf16
    unsigned int u = __builtin_bit_cast(unsigned int, f);
    return (unsigned short)((u + 0x7FFFu + ((u >> 16) & 1u)) >> 16);
}
__device__ __forceinline__ float bf2f(unsigned short h) {
    return __builtin_bit_cast(float, (unsigned int)h << 16);
}

__device__ __forceinline__ void load_edge(const void* adj, int int32_mode,
                                          int e, int E, int& r, int& c) {
    if (int32_mode) {
        const int* a = (const int*)adj;
        r = a[e]; c = a[(size_t)E + e];
    } else {
        const long long* a = (const long long*)adj;
        r = (int)a[e]; c = (int)a[(size_t)E + e];
    }
}

// ---------------------------------------------------------------------------
// W [40][512] f32 -> Wb [48][512] bf16 (rows 40..47 zero). Also zeroes the
// tiny control scalars (removes a separate memset dispatch).
// ---------------------------------------------------------------------------
__global__ void wconv_kernel(const float* __restrict__ W,
                             unsigned short* __restrict__ Wb,
                             unsigned int* __restrict__ flag,
                             int* __restrict__ ovf_cnt) {
    int i = blockIdx.x * blockDim.x + threadIdx.x;
    if (i == 0) { *flag = 0u; *ovf_cnt = 0; }
    if (i >= NPAD * NFEAT) return;
    int n = i >> 9;
    float v = (n < NCLS) ? W[i] : 0.0f;
    Wb[i] = f2bf(v);
}

// ===========================================================================
// FUSED: blocks [0, P1B) run edge-partition phase 1; blocks [P1B, ...) run
// the LDS-staged MFMA GEMM. Phase-1 blocks first so they start immediately.
// ===========================================================================
__global__ __launch_bounds__(256) void fused_gemm_phase1(
        const float* __restrict__ x, const unsigned short* __restrict__ Wb,
        unsigned short* __restrict__ xwb, const void* __restrict__ adj,
        unsigned int* __restrict__ slices, int* __restrict__ slice_cnt,
        unsigned long long* __restrict__ ovf, int* __restrict__ ovf_cnt,
        int N, int E, int NB) {
    __shared__ unsigned short sm_xs[64][XSC];   // 66.5 KB; aliased by phase 1

    if (blockIdx.x < P1B) {
        if (slice_cnt == nullptr || E <= 0) return;   // gemm-only invocation
        // ----- phase 1: private-slice edge partition (LDS cursors) -----
        int* lcur = (int*)(&sm_xs[0][0]);             // [0,512) cursors
        unsigned int* det = (unsigned int*)(lcur + 512);
        const int blk = blockIdx.x;
        for (int i = threadIdx.x; i < NB; i += 256) lcur[i] = 0;
        if (threadIdx.x == 0) *det = 0u;
        __syncthreads();
        // inline dtype detect: odd 32-bit words all-zero <=> int64 storage
        const unsigned int* aw = (const unsigned int*)adj;
        unsigned int v = aw[2 * threadIdx.x + 1] | aw[2 * (threadIdx.x + 256) + 1];
        if (v) atomicOr(det, 1u);
        __syncthreads();
        const int m32 = (*det != 0);
        const int chunk = (E + P1B - 1) / P1B;
        const int e0 = blk * chunk;
        const int e1 = min(E, e0 + chunk);
        for (int e = e0 + (int)threadIdx.x; e < e1; e += 256) {
            int r, c;
            load_edge(adj, m32, e, E, r, c);
            if (r == c) continue;
            if ((unsigned)r >= (unsigned)N || (unsigned)c >= (unsigned)N) continue;
            int b = c >> 8;
            unsigned int p = ((unsigned int)(c & 255) << 17) | (unsigned int)r;
            int pos = atomicAdd(&lcur[b], 1);            // LDS atomic
            if (pos < SLICE_CAP) {
                slices[((size_t)b * P1B + blk) * SLICE_CAP + pos] = p;
            } else {
                int oi = atomicAdd(ovf_cnt, 1);
                if (oi < OVF_CAP)
                    ovf[oi] = ((unsigned long long)b << 32) | p;
            }
        }
        __syncthreads();
        for (int i = threadIdx.x; i < NB; i += 256)
            slice_cnt[(size_t)i * P1B + blk] = min(lcur[i], SLICE_CAP);
        return;
    }

    // ----- gemm role: stage 64x512 f32 tile -> bf16 LDS (coalesced), MFMA -----
    const int t = threadIdx.x;
    const int mbase = (int)(blockIdx.x - P1B) * 64;
    if (mbase >= N) return;
    const int rowlim = N - 1;
    for (int i = t; i < 64 * 128; i += 256) {       // 8192 float4s, 32/thread
        int row = i >> 7;
        int c4  = i & 127;
        int grow = mbase + row; if (grow > rowlim) grow = rowlim;
        float4 v = *reinterpret_cast<const float4*>(
            x + (size_t)grow * NFEAT + (c4 << 2));
        ushort4 h;
        h.x = f2bf(v.x); h.y = f2bf(v.y); h.z = f2bf(v.z); h.w = f2bf(v.w);
        *reinterpret_cast<ushort4*>(&sm_xs[row][c4 << 2]) = h;
    }
    __syncthreads();

    const int w = t >> 6, lane = t & 63;
    const int row = lane & 15, ks = lane >> 4;      // fragment coords
    const unsigned short* xr  = &sm_xs[w * 16 + row][ks * 8];
    const unsigned short* wb0 = Wb + (size_t)row * NFEAT + ks * 8;
    const unsigned short* wb1 = wb0 + (size_t)16 * NFEAT;
    const unsigned short* wb2 = wb0 + (size_t)32 * NFEAT;

    f32x4 acc0 = {0.f, 0.f, 0.f, 0.f};
    f32x4 acc1 = {0.f, 0.f, 0.f, 0.f};
    f32x4 acc2 = {0.f, 0.f, 0.f, 0.f};

    for (int kk = 0; kk < NFEAT; kk += 32) {
        bf16x8 a  = *reinterpret_cast<const bf16x8*>(xr + kk);
        bf16x8 b0 = *reinterpret_cast<const bf16x8*>(wb0 + kk);
        bf16x8 b1 = *reinterpret_cast<const bf16x8*>(wb1 + kk);
        bf16x8 b2 = *reinterpret_cast<const bf16x8*>(wb2 + kk);
        acc0 = __builtin_amdgcn_mfma_f32_16x16x32_bf16(a, b0, acc0, 0, 0, 0);
        acc1 = __builtin_amdgcn_mfma_f32_16x16x32_bf16(a, b1, acc1, 0, 0, 0);
        acc2 = __builtin_amdgcn_mfma_f32_16x16x32_bf16(a, b2, acc2, 0, 0, 0);
    }

    const int m0 = mbase + w * 16;
    const int ccol = row;
#pragma unroll
    for (int i = 0; i < 4; ++i) {
        int crow = m0 + ks * 4 + i;
        if (crow < N) {
            unsigned short* orow = xwb + (size_t)crow * NCLS;
            orow[ccol]      = f2bf(acc0[i]);
            orow[16 + ccol] = f2bf(acc1[i]);
            if (ccol < 8) orow[32 + ccol] = f2bf(acc2[i]);
        }
    }
}

// ---------------------------------------------------------------------------
// Phase 2: one block per bucket; fixed region bs = b*BCAP (no scan kernels).
// ---------------------------------------------------------------------------
__global__ void phase2_kernel(const unsigned int* __restrict__ slices,
                              const int* __restrict__ slice_cnt,
                              const unsigned long long* __restrict__ ovf,
                              const int* __restrict__ ovf_cnt,
                              int* __restrict__ starts,
                              int* __restrict__ cnt,
                              int* __restrict__ src, int N) {
    __shared__ int hist[NCB];
    __shared__ int lscan[NCB];
    __shared__ int cur[NCB];
    const int b = blockIdx.x;
    const int t = threadIdx.x;            // blockDim.x == 256 == NCB == P1B
    hist[t] = 0;
    __syncthreads();

    const int myk = slice_cnt[(size_t)b * P1B + t];   // thread t owns slice t
    const unsigned int* mysl = slices + ((size_t)b * P1B + t) * SLICE_CAP;
    for (int i = 0; i < myk; ++i)
        atomicAdd(&hist[mysl[i] >> 17], 1);
    const int no = min(*ovf_cnt, OVF_CAP);
    for (int i = t; i < no; i += 256)
        if ((int)(ovf[i] >> 32) == b)
            atomicAdd(&hist[((unsigned int)ovf[i]) >> 17], 1);
    __syncthreads();

    int h = hist[t];
    lscan[t] = h;
    __syncthreads();
    for (int o = 1; o < 256; o <<= 1) {
        int v = (t >= o) ? lscan[t - o] : 0;
        __syncthreads();
        lscan[t] += v;
        __syncthreads();
    }
    int excl = lscan[t] - h;
    cur[t] = excl;
    const int bs = b * BCAP;
    const int c0 = b * NCB;
    if (c0 + t < N) {
        starts[c0 + t] = bs + excl;
        cnt[c0 + t] = h;
    }
    __syncthreads();

    for (int i = 0; i < myk; ++i) {
        unsigned int p = mysl[i];
        int pos = atomicAdd(&cur[p >> 17], 1);       // LDS atomic
        if (pos < BCAP) src[bs + pos] = (int)(p & 0x1FFFFu);
    }
    for (int i = t; i < no; i += 256) {
        if ((int)(ovf[i] >> 32) == b) {
            unsigned int p = (unsigned int)ovf[i];
            int pos = atomicAdd(&cur[p >> 17], 1);
            if (pos < BCAP) src[bs + pos] = (int)(p & 0x1FFFFu);
        }
    }
}

// ===========================================================================
// LEGACY DIRECT PATH (fallback only)
// ===========================================================================
__global__ void detect_kernel(const unsigned int* __restrict__ w,
                              unsigned int* __restrict__ flag) {
    unsigned int v = 0;
    for (int i = 1 + 2 * (int)threadIdx.x; i < 65536; i += 2 * (int)blockDim.x)
        v |= w[i];
    if (v) atomicOr(flag, 1u);
}

__global__ void fused_bucket_kernel(const void* __restrict__ adj,
                                    const unsigned int* __restrict__ flag,
                                    int* __restrict__ cnt,
                                    int* __restrict__ src2, int E, int N) {
    int e = blockIdx.x * blockDim.x + threadIdx.x;
    if (e >= E) return;
    int r, c;
    load_edge(adj, *flag, e, E, r, c);
    if (r == c) return;
    if ((unsigned)r >= (unsigned)N || (unsigned)c >= (unsigned)N) return;
    int pos = atomicAdd(&cnt[c], 1);
    if (pos < DM) src2[(size_t)c * DM + pos] = r;
}

// ---------------------------------------------------------------------------
// Gather: one wave per node. lane = (edge-group g 0..5, class-quad cl 0..9).
// 12 edges in flight per iteration; rows read as ushort4 (8 B); 3-round
// shfl reduction across groups; float4 output writes by lanes 0..9.
// dm > 0: direct mode; dm == 0: CSR mode.
// ---------------------------------------------------------------------------
__global__ void gather_kernel(const unsigned short* __restrict__ xwb,
                              const int* __restrict__ starts,
                              const int* __restrict__ deg,
                              const int* __restrict__ src,
                              const float* __restrict__ bias,
                              float* __restrict__ out, int N, int dm) {
    int wid = (blockIdx.x * blockDim.x + threadIdx.x) >> 6;
    int lane = threadIdx.x & 63;
    if (wid >= N) return;
    int start, d;
    if (dm > 0) {
        start = wid * dm;
        d = min(deg[wid], dm);
    } else {
        start = starts[wid];
        d = deg[wid];
    }
    start = __builtin_amdgcn_readfirstlane(start);
    d     = __builtin_amdgcn_readfirstlane(d);

    const int g  = lane / 10;        // 0..5 edge groups; g==6 (lanes 60-63) idle
    const int cl = lane % 10;        // class quad
    const bool lact = (g < 6);
    float a0 = 0.f, a1 = 0.f, a2 = 0.f, a3 = 0.f;

    if (g == 0) {                    // self-loop row
        ushort4 v = *reinterpret_cast<const ushort4*>(
            xwb + (size_t)wid * NCLS + cl * 4);
        a0 = bf2f(v.x); a1 = bf2f(v.y); a2 = bf2f(v.z); a3 = bf2f(v.w);
    }

    const int* sp = src + start;
    for (int e = 0; e < d; e += 12) {
        int i0 = e + g, i1 = e + 6 + g;
        if (lact && i0 < d) {
            int r = sp[i0];
            ushort4 v = *reinterpret_cast<const ushort4*>(
                xwb + (size_t)r * NCLS + cl * 4);
            a0 += bf2f(v.x); a1 += bf2f(v.y); a2 += bf2f(v.z); a3 += bf2f(v.w);
        }
        if (lact && i1 < d) {
            int r = sp[i1];
            ushort4 v = *reinterpret_cast<const ushort4*>(
                xwb + (size_t)r * NCLS + cl * 4);
            a0 += bf2f(v.x); a1 += bf2f(v.y); a2 += bf2f(v.z); a3 += bf2f(v.w);
        }
    }

    // reduce groups: g0..g5 live at lane strides of 10
    a0 += __shfl_down(a0, 30); a1 += __shfl_down(a1, 30);
    a2 += __shfl_down(a2, 30); a3 += __shfl_down(a3, 30);
    {
        float u0 = __shfl_down(a0, 10), v0 = __shfl_down(a0, 20);
        float u1 = __shfl_down(a1, 10), v1 = __shfl_down(a1, 20);
        float u2 = __shfl_down(a2, 10), v2 = __shfl_down(a2, 20);
        float u3 = __shfl_down(a3, 10), v3 = __shfl_down(a3, 20);
        a0 += u0 + v0; a1 += u1 + v1; a2 += u2 + v2; a3 += u3 + v3;
    }

    if (lane < 10) {
        float scale = 1.0f / (float)(d + 1);
        float4 bb = *reinterpret_cast<const float4*>(bias + cl * 4);
        float4 o;
        o.x = fmaf(scale, a0, bb.x);
        o.y = fmaf(scale, a1, bb.y);
        o.z = fmaf(scale, a2, bb.z);
        o.w = fmaf(scale, a3, bb.w);
        *reinterpret_cast<float4*>(out + (size_t)wid * NCLS + cl * 4) = o;
    }
}

extern "C" void kernel_launch(void* const* d_in, const int* in_sizes, int n_in,
                              void* d_out, int out_size, void* d_ws, size_t ws_size,
                              hipStream_t stream) {
    const float* x   = (const float*)d_in[0];
    const void*  adj = d_in[1];
    const float* W   = (const float*)d_in[2];
    const float* b   = (const float*)d_in[3];
    float* out = (float*)d_out;

    const int N = in_sizes[0] / NFEAT;   // 100000
    const int E = in_sizes[1] / 2;       // 3200000
    const int NB = (N + NCB - 1) / NCB;  // 391 coarse buckets
    const int GEMMB = (N + 63) / 64;     // 64 rows per gemm block

    char* ws = (char*)d_ws;
    size_t off = 0;
    auto alloc = [&](size_t bytes) { char* p = ws + off; off += (bytes + 15) & ~size_t(15); return p; };

    unsigned short* xwb = (unsigned short*)alloc((size_t)N * NCLS * 2);   // 8 MB
    int*   cnt          = (int*)  alloc((size_t)N * sizeof(int));
    unsigned int* flag  = (unsigned int*)alloc(16);
    int*   ovf_cnt      = (int*)  alloc(16);
    unsigned short* Wb  = (unsigned short*)alloc((size_t)NPAD * NFEAT * 2);

    const size_t part_need = off
        + (((size_t)NB * P1B * SLICE_CAP * 4 + 15) & ~size_t(15))   // slices ~32 MB
        + (((size_t)NB * P1B * 4 + 15) & ~size_t(15))               // slice_cnt
        + (((size_t)N * 4 + 15) & ~size_t(15))                      // starts
        + (((size_t)NB * BCAP * 4 + 15) & ~size_t(15))              // src 25.6 MB
        + (size_t)OVF_CAP * 8;                                      // ovf ring
    const bool partition = (N <= NCB * 512) && (NB <= 512) && (E >= 512)
                           && (part_need <= ws_size);
    const size_t direct_need = off + (size_t)N * DM * sizeof(int);
    const bool direct = !partition && (direct_need <= ws_size);

    wconv_kernel<<<(NPAD * NFEAT + 255) / 256, 256, 0, stream>>>(W, Wb, flag, ovf_cnt);

    if (partition) {
        unsigned int* slices = (unsigned int*)alloc((size_t)NB * P1B * SLICE_CAP * 4);
        int* slice_cnt = (int*)alloc((size_t)NB * P1B * 4);
        int* starts = (int*)alloc((size_t)N * 4);
        int* src    = (int*)alloc((size_t)NB * BCAP * 4);
        unsigned long long* ovf = (unsigned long long*)alloc((size_t)OVF_CAP * 8);

        fused_gemm_phase1<<<P1B + GEMMB, 256, 0, stream>>>(
            x, Wb, xwb, adj, slices, slice_cnt, ovf, ovf_cnt, N, E, NB);
        phase2_kernel<<<NB, 256, 0, stream>>>(slices, slice_cnt, ovf, ovf_cnt,
                                              starts, cnt, src, N);
        gather_kernel<<<(N * 64 + 255) / 256, 256, 0, stream>>>(
            xwb, starts, cnt, src, b, out, N, 0);
    } else if (direct) {
        int* src2 = (int*)alloc((size_t)N * DM * sizeof(int));
        hipMemsetAsync(cnt, 0, (size_t)N * sizeof(int), stream);
        detect_kernel<<<1, 512, 0, stream>>>((const unsigned int*)adj, flag);
        fused_gemm_phase1<<<P1B + GEMMB, 256, 0, stream>>>(
            x, Wb, xwb, adj, nullptr, nullptr, nullptr, ovf_cnt, N, 0, NB);
        fused_bucket_kernel<<<(E + 255) / 256, 256, 0, stream>>>(adj, flag, cnt, src2, E, N);
        gather_kernel<<<(N * 64 + 255) / 256, 256, 0, stream>>>(
            xwb, nullptr, cnt, src2, b, out, N, DM);
    }
}

// Round 10
// 231.296 us; speedup vs baseline: 29.9463x; 1.0321x over previous
//
#include <hip/hip_runtime.h>

#define NFEAT 512
#define NCLS  40
#define NPAD  48          // NCLS padded to 3 MFMA n-tiles of 16
#define DM 128            // padded bucket width (legacy direct path)

// partition path parameters
#define NCB        256    // nodes per coarse bucket (c >> 8)
#define SLICE_CAP  80     // per (block,bucket) private slice capacity (mean 32)
#define P1B        256    // phase-1 block count
#define BCAP       16384  // fixed src region per bucket (mean 8192)
#define OVF_CAP    65536  // overflow ring capacity (virtually never used)

#define KHALF 256         // K columns staged per round (2 rounds of 256)

typedef __attribute__((ext_vector_type(8))) short bf16x8;   // 8 bf16 (4 VGPRs)
typedef __attribute__((ext_vector_type(4))) float f32x4;

__device__ __forceinline__ unsigned short f2bf(float f) {   // RNE f32->bf16
    unsigned int u = __builtin_bit_cast(unsigned int, f);
    return (unsigned short)((u + 0x7FFFu + ((u >> 16) & 1u)) >> 16);
}
__device__ __forceinline__ float bf2f(unsigned short h) {
    return __builtin_bit_cast(float, (unsigned int)h << 16);
}

__device__ __forceinline__ void load_edge(const void* adj, int int32_mode,
                                          int e, int E, int& r, int& c) {
    if (int32_mode) {
        const int* a = (const int*)adj;
        r = a[e]; c = a[(size_t)E + e];
    } else {
        const long long* a = (const long long*)adj;
        r = (int)a[e]; c = (int)a[(size_t)E + e];
    }
}

// ---------------------------------------------------------------------------
// W [40][512] f32 -> Wb [48][512] bf16 (rows 40..47 zero) + zero scalars.
// ---------------------------------------------------------------------------
__global__ void wconv_kernel(const float* __restrict__ W,
                             unsigned short* __restrict__ Wb,
                             unsigned int* __restrict__ flag,
                             int* __restrict__ ovf_cnt) {
    int i = blockIdx.x * blockDim.x + threadIdx.x;
    if (i == 0) { *flag = 0u; *ovf_cnt = 0; }
    if (i >= NPAD * NFEAT) return;
    int n = i >> 9;
    float v = (n < NCLS) ? W[i] : 0.0f;
    Wb[i] = f2bf(v);
}

// ===========================================================================
// FUSED: blocks [0, P1B) run edge-partition phase 1; blocks [P1B, ...) run
// the LDS-staged MFMA GEMM (two K-halves, 32 KB LDS, XOR-swizzled slots).
// ===========================================================================
__global__ __launch_bounds__(256) void fused_gemm_phase1(
        const float* __restrict__ x, const unsigned short* __restrict__ Wb,
        unsigned short* __restrict__ xwb, const void* __restrict__ adj,
        unsigned int* __restrict__ slices, int* __restrict__ slice_cnt,
        unsigned long long* __restrict__ ovf, int* __restrict__ ovf_cnt,
        int N, int E, int NB) {
    // gemm tile: 64 rows x 256 bf16 cols, stored as 32 swizzled 16B slots/row
    __shared__ unsigned short sm[64 * KHALF];   // 32 KB (aliased by phase 1)

    if (blockIdx.x < P1B) {
        if (slice_cnt == nullptr || E <= 0) return;   // gemm-only invocation
        // ----- phase 1: private-slice edge partition (LDS cursors) -----
        int* lcur = (int*)sm;                         // [0,512) cursors
        unsigned int* det = (unsigned int*)(lcur + 512);
        const int blk = blockIdx.x;
        for (int i = threadIdx.x; i < NB; i += 256) lcur[i] = 0;
        if (threadIdx.x == 0) *det = 0u;
        __syncthreads();
        // inline dtype detect: odd 32-bit words all-zero <=> int64 storage
        const unsigned int* aw = (const unsigned int*)adj;
        unsigned int v = aw[2 * threadIdx.x + 1] | aw[2 * (threadIdx.x + 256) + 1];
        if (v) atomicOr(det, 1u);
        __syncthreads();
        const int m32 = (*det != 0);
        const int chunk = (E + P1B - 1) / P1B;
        const int e0 = blk * chunk;
        const int e1 = min(E, e0 + chunk);
        for (int e = e0 + (int)threadIdx.x; e < e1; e += 256) {
            int r, c;
            load_edge(adj, m32, e, E, r, c);
            if (r == c) continue;
            if ((unsigned)r >= (unsigned)N || (unsigned)c >= (unsigned)N) continue;
            int b = c >> 8;
            unsigned int p = ((unsigned int)(c & 255) << 17) | (unsigned int)r;
            int pos = atomicAdd(&lcur[b], 1);            // LDS atomic
            if (pos < SLICE_CAP) {
                slices[((size_t)b * P1B + blk) * SLICE_CAP + pos] = p;
            } else {
                int oi = atomicAdd(ovf_cnt, 1);
                if (oi < OVF_CAP)
                    ovf[oi] = ((unsigned long long)b << 32) | p;
            }
        }
        __syncthreads();
        for (int i = threadIdx.x; i < NB; i += 256)
            slice_cnt[(size_t)i * P1B + blk] = min(lcur[i], SLICE_CAP);
        return;
    }

    // ----- gemm role: 64-row tile, 2 staged K-halves, XOR-swizzled LDS -----
    const int t = threadIdx.x;
    const int mbase = (int)(blockIdx.x - P1B) * 64;
    if (mbase >= N) return;
    const int rowlim = N - 1;

    const int w = t >> 6, lane = t & 63;
    const int frow = lane & 15, ks = lane >> 4;     // fragment coords
    const unsigned short* wrow = Wb + (size_t)frow * NFEAT + ks * 8;

    f32x4 acc0 = {0.f, 0.f, 0.f, 0.f};
    f32x4 acc1 = {0.f, 0.f, 0.f, 0.f};
    f32x4 acc2 = {0.f, 0.f, 0.f, 0.f};

    // per-thread stage coords: 64 lanes of a wave cover one row (c4 = lane)
    const int sc4 = t & 63;                 // float4 col within half-tile
    const int srow0 = t >> 6;               // + 4*it
    // swizzled LDS byte offset for (row, c4): slot = c4>>1 (^ row&7), half = c4&1
    for (int h = 0; h < 2; ++h) {
        const int koff = h * KHALF;
        float4 v[16];
#pragma unroll
        for (int it = 0; it < 16; ++it) {
            int row = srow0 + it * 4;
            int grow = mbase + row; if (grow > rowlim) grow = rowlim;
            v[it] = *reinterpret_cast<const float4*>(
                x + (size_t)grow * NFEAT + koff + (sc4 << 2));
        }
        if (h) __syncthreads();             // prior MFMA reads done
#pragma unroll
        for (int it = 0; it < 16; ++it) {
            int row = srow0 + it * 4;
            ushort4 hv;
            hv.x = f2bf(v[it].x); hv.y = f2bf(v[it].y);
            hv.z = f2bf(v[it].z); hv.w = f2bf(v[it].w);
            int byte = (row << 9) | ((((sc4 >> 1) ^ (row & 7)) << 4) | ((sc4 & 1) << 3));
            *reinterpret_cast<ushort4*>((char*)sm + byte) = hv;
        }
        __syncthreads();

        const char* arow = (const char*)sm + ((w * 16 + frow) << 9);
#pragma unroll
        for (int st = 0; st < KHALF / 32; ++st) {
            int slot = (ks + 4 * st) ^ (frow & 7);
            bf16x8 a = *reinterpret_cast<const bf16x8*>(arow + (slot << 4));
            const unsigned short* wk = wrow + koff + st * 32;
            bf16x8 b0 = *reinterpret_cast<const bf16x8*>(wk);
            bf16x8 b1 = *reinterpret_cast<const bf16x8*>(wk + 16 * NFEAT);
            bf16x8 b2 = *reinterpret_cast<const bf16x8*>(wk + 32 * NFEAT);
            acc0 = __builtin_amdgcn_mfma_f32_16x16x32_bf16(a, b0, acc0, 0, 0, 0);
            acc1 = __builtin_amdgcn_mfma_f32_16x16x32_bf16(a, b1, acc1, 0, 0, 0);
            acc2 = __builtin_amdgcn_mfma_f32_16x16x32_bf16(a, b2, acc2, 0, 0, 0);
        }
    }

    const int m0 = mbase + w * 16;
    const int ccol = frow;
#pragma unroll
    for (int i = 0; i < 4; ++i) {
        int crow = m0 + ks * 4 + i;
        if (crow < N) {
            unsigned short* orow = xwb + (size_t)crow * NCLS;
            orow[ccol]      = f2bf(acc0[i]);
            orow[16 + ccol] = f2bf(acc1[i]);
            if (ccol < 8) orow[32 + ccol] = f2bf(acc2[i]);
        }
    }
}

// ---------------------------------------------------------------------------
// Phase 2: one block per bucket; fixed region bs = b*BCAP.
// ---------------------------------------------------------------------------
__global__ void phase2_kernel(const unsigned int* __restrict__ slices,
                              const int* __restrict__ slice_cnt,
                              const unsigned long long* __restrict__ ovf,
                              const int* __restrict__ ovf_cnt,
                              int* __restrict__ starts,
                              int* __restrict__ cnt,
                              int* __restrict__ src, int N) {
    __shared__ int hist[NCB];
    __shared__ int lscan[NCB];
    __shared__ int cur[NCB];
    const int b = blockIdx.x;
    const int t = threadIdx.x;            // blockDim.x == 256 == NCB == P1B
    hist[t] = 0;
    __syncthreads();

    const int myk = slice_cnt[(size_t)b * P1B + t];   // thread t owns slice t
    const unsigned int* mysl = slices + ((size_t)b * P1B + t) * SLICE_CAP;
    for (int i = 0; i < myk; ++i)
        atomicAdd(&hist[mysl[i] >> 17], 1);
    const int no = min(*ovf_cnt, OVF_CAP);
    for (int i = t; i < no; i += 256)
        if ((int)(ovf[i] >> 32) == b)
            atomicAdd(&hist[((unsigned int)ovf[i]) >> 17], 1);
    __syncthreads();

    int h = hist[t];
    lscan[t] = h;
    __syncthreads();
    for (int o = 1; o < 256; o <<= 1) {
        int v = (t >= o) ? lscan[t - o] : 0;
        __syncthreads();
        lscan[t] += v;
        __syncthreads();
    }
    int excl = lscan[t] - h;
    cur[t] = excl;
    const int bs = b * BCAP;
    const int c0 = b * NCB;
    if (c0 + t < N) {
        starts[c0 + t] = bs + excl;
        cnt[c0 + t] = h;
    }
    __syncthreads();

    for (int i = 0; i < myk; ++i) {
        unsigned int p = mysl[i];
        int pos = atomicAdd(&cur[p >> 17], 1);       // LDS atomic
        if (pos < BCAP) src[bs + pos] = (int)(p & 0x1FFFFu);
    }
    for (int i = t; i < no; i += 256) {
        if ((int)(ovf[i] >> 32) == b) {
            unsigned int p = (unsigned int)ovf[i];
            int pos = atomicAdd(&cur[p >> 17], 1);
            if (pos < BCAP) src[bs + pos] = (int)(p & 0x1FFFFu);
        }
    }
}

// ===========================================================================
// LEGACY DIRECT PATH (fallback only)
// ===========================================================================
__global__ void detect_kernel(const unsigned int* __restrict__ w,
                              unsigned int* __restrict__ flag) {
    unsigned int v = 0;
    for (int i = 1 + 2 * (int)threadIdx.x; i < 65536; i += 2 * (int)blockDim.x)
        v |= w[i];
    if (v) atomicOr(flag, 1u);
}

__global__ void fused_bucket_kernel(const void* __restrict__ adj,
                                    const unsigned int* __restrict__ flag,
                                    int* __restrict__ cnt,
                                    int* __restrict__ src2, int E, int N) {
    int e = blockIdx.x * blockDim.x + threadIdx.x;
    if (e >= E) return;
    int r, c;
    load_edge(adj, *flag, e, E, r, c);
    if (r == c) return;
    if ((unsigned)r >= (unsigned)N || (unsigned)c >= (unsigned)N) return;
    int pos = atomicAdd(&cnt[c], 1);
    if (pos < DM) src2[(size_t)c * DM + pos] = r;
}

// ---------------------------------------------------------------------------
// Gather: one wave per node. lane = (edge-group g 0..5, class-quad cl 0..9).
// ---------------------------------------------------------------------------
__global__ void gather_kernel(const unsigned short* __restrict__ xwb,
                              const int* __restrict__ starts,
                              const int* __restrict__ deg,
                              const int* __restrict__ src,
                              const float* __restrict__ bias,
                              float* __restrict__ out, int N, int dm) {
    int wid = (blockIdx.x * blockDim.x + threadIdx.x) >> 6;
    int lane = threadIdx.x & 63;
    if (wid >= N) return;
    int start, d;
    if (dm > 0) {
        start = wid * dm;
        d = min(deg[wid], dm);
    } else {
        start = starts[wid];
        d = deg[wid];
    }
    start = __builtin_amdgcn_readfirstlane(start);
    d     = __builtin_amdgcn_readfirstlane(d);

    const int g  = lane / 10;        // 0..5 edge groups; lanes 60-63 idle
    const int cl = lane % 10;        // class quad
    const bool lact = (g < 6);
    float a0 = 0.f, a1 = 0.f, a2 = 0.f, a3 = 0.f;

    if (g == 0) {                    // self-loop row
        ushort4 v = *reinterpret_cast<const ushort4*>(
            xwb + (size_t)wid * NCLS + cl * 4);
        a0 = bf2f(v.x); a1 = bf2f(v.y); a2 = bf2f(v.z); a3 = bf2f(v.w);
    }

    const int* sp = src + start;
    for (int e = 0; e < d; e += 12) {
        int i0 = e + g, i1 = e + 6 + g;
        if (lact && i0 < d) {
            int r = sp[i0];
            ushort4 v = *reinterpret_cast<const ushort4*>(
                xwb + (size_t)r * NCLS + cl * 4);
            a0 += bf2f(v.x); a1 += bf2f(v.y); a2 += bf2f(v.z); a3 += bf2f(v.w);
        }
        if (lact && i1 < d) {
            int r = sp[i1];
            ushort4 v = *reinterpret_cast<const ushort4*>(
                xwb + (size_t)r * NCLS + cl * 4);
            a0 += bf2f(v.x); a1 += bf2f(v.y); a2 += bf2f(v.z); a3 += bf2f(v.w);
        }
    }

    a0 += __shfl_down(a0, 30); a1 += __shfl_down(a1, 30);
    a2 += __shfl_down(a2, 30); a3 += __shfl_down(a3, 30);
    {
        float u0 = __shfl_down(a0, 10), v0 = __shfl_down(a0, 20);
        float u1 = __shfl_down(a1, 10), v1 = __shfl_down(a1, 20);
        float u2 = __shfl_down(a2, 10), v2 = __shfl_down(a2, 20);
        float u3 = __shfl_down(a3, 10), v3 = __shfl_down(a3, 20);
        a0 += u0 + v0; a1 += u1 + v1; a2 += u2 + v2; a3 += u3 + v3;
    }

    if (lane < 10) {
        float scale = 1.0f / (float)(d + 1);
        float4 bb = *reinterpret_cast<const float4*>(bias + cl * 4);
        float4 o;
        o.x = fmaf(scale, a0, bb.x);
        o.y = fmaf(scale, a1, bb.y);
        o.z = fmaf(scale, a2, bb.z);
        o.w = fmaf(scale, a3, bb.w);
        *reinterpret_cast<float4*>(out + (size_t)wid * NCLS + cl * 4) = o;
    }
}

extern "C" void kernel_launch(void* const* d_in, const int* in_sizes, int n_in,
                              void* d_out, int out_size, void* d_ws, size_t ws_size,
                              hipStream_t stream) {
    const float* x   = (const float*)d_in[0];
    const void*  adj = d_in[1];
    const float* W   = (const float*)d_in[2];
    const float* b   = (const float*)d_in[3];
    float* out = (float*)d_out;

    const int N = in_sizes[0] / NFEAT;   // 100000
    const int E = in_sizes[1] / 2;       // 3200000
    const int NB = (N + NCB - 1) / NCB;  // 391 coarse buckets
    const int GEMMB = (N + 63) / 64;     // 64 rows per gemm block

    char* ws = (char*)d_ws;
    size_t off = 0;
    auto alloc = [&](size_t bytes) { char* p = ws + off; off += (bytes + 15) & ~size_t(15); return p; };

    unsigned short* xwb = (unsigned short*)alloc((size_t)N * NCLS * 2);   // 8 MB
    int*   cnt          = (int*)  alloc((size_t)N * sizeof(int));
    unsigned int* flag  = (unsigned int*)alloc(16);
    int*   ovf_cnt      = (int*)  alloc(16);
    unsigned short* Wb  = (unsigned short*)alloc((size_t)NPAD * NFEAT * 2);

    const size_t part_need = off
        + (((size_t)NB * P1B * SLICE_CAP * 4 + 15) & ~size_t(15))   // slices ~32 MB
        + (((size_t)NB * P1B * 4 + 15) & ~size_t(15))               // slice_cnt
        + (((size_t)N * 4 + 15) & ~size_t(15))                      // starts
        + (((size_t)NB * BCAP * 4 + 15) & ~size_t(15))              // src 25.6 MB
        + (size_t)OVF_CAP * 8;                                      // ovf ring
    const bool partition = (N <= NCB * 512) && (NB <= 512) && (E >= 512)
                           && (part_need <= ws_size);
    const size_t direct_need = off + (size_t)N * DM * sizeof(int);
    const bool direct = !partition && (direct_need <= ws_size);

    wconv_kernel<<<(NPAD * NFEAT + 255) / 256, 256, 0, stream>>>(W, Wb, flag, ovf_cnt);

    if (partition) {
        unsigned int* slices = (unsigned int*)alloc((size_t)NB * P1B * SLICE_CAP * 4);
        int* slice_cnt = (int*)alloc((size_t)NB * P1B * 4);
        int* starts = (int*)alloc((size_t)N * 4);
        int* src    = (int*)alloc((size_t)NB * BCAP * 4);
        unsigned long long* ovf = (unsigned long long*)alloc((size_t)OVF_CAP * 8);

        fused_gemm_phase1<<<P1B + GEMMB, 256, 0, stream>>>(
            x, Wb, xwb, adj, slices, slice_cnt, ovf, ovf_cnt, N, E, NB);
        phase2_kernel<<<NB, 256, 0, stream>>>(slices, slice_cnt, ovf, ovf_cnt,
                                              starts, cnt, src, N);
        gather_kernel<<<(N * 64 + 255) / 256, 256, 0, stream>>>(
            xwb, starts, cnt, src, b, out, N, 0);
    } else if (direct) {
        int* src2 = (int*)alloc((size_t)N * DM * sizeof(int));
        hipMemsetAsync(cnt, 0, (size_t)N * sizeof(int), stream);
        detect_kernel<<<1, 512, 0, stream>>>((const unsigned int*)adj, flag);
        fused_gemm_phase1<<<P1B + GEMMB, 256, 0, stream>>>(
            x, Wb, xwb, adj, nullptr, nullptr, nullptr, ovf_cnt, N, 0, NB);
        fused_bucket_kernel<<<(E + 255) / 256, 256, 0, stream>>>(adj, flag, cnt, src2, E, N);
        gather_kernel<<<(N * 64 + 255) / 256, 256, 0, stream>>>(
            xwb, nullptr, cnt, src2, b, out, N, DM);
    }
}